// Round 1
// baseline (468.934 us; speedup 1.0000x reference)
//
#include <hip/hip_runtime.h>
#include <cstdint>
#include <cstddef>

#define N_NODES 8192
#define IN_DIM 128
#define H 32

__device__ __forceinline__ float lrelu(float x) { return x >= 0.0f ? x : 0.2f * x; }
__device__ __forceinline__ float sigmoidf_(float x) { return 1.0f / (1.0f + __expf(-x)); }
__device__ __forceinline__ float tanh_fast(float x) { return 1.0f - 2.0f / (1.0f + __expf(2.0f * x)); }

// ---------------------------------------------------------------------------
// K1: Wh1 = x@W1^T + b1, Wh2 = x@W2^T + b2, s1 = Wh1@a1, s2 = Wh2@a2
// block = 256 threads = 8 rows x 32 h-lanes
// ---------------------------------------------------------------------------
__global__ __launch_bounds__(256) void k1_wh_s(
    const float* __restrict__ x,
    const float* __restrict__ W1, const float* __restrict__ b1, const float* __restrict__ a1,
    const float* __restrict__ W2, const float* __restrict__ b2, const float* __restrict__ a2,
    float* __restrict__ Wh1, float* __restrict__ Wh2,
    float* __restrict__ s1, float* __restrict__ s2)
{
    __shared__ float xl[8 * IN_DIM];
    int tid = threadIdx.x;
    int row0 = blockIdx.x * 8;

    ((float4*)xl)[tid] = ((const float4*)(x + (size_t)row0 * IN_DIM))[tid];
    __syncthreads();

    int r = tid >> 5, h = tid & 31;
    const float* xr = xl + r * IN_DIM;
    const float* w1r = W1 + h * IN_DIM;
    const float* w2r = W2 + h * IN_DIM;
    float d1 = 0.f, d2 = 0.f;
#pragma unroll 8
    for (int k = 0; k < IN_DIM; k += 4) {
        float4 xv = *(const float4*)(xr + k);
        float4 wa = *(const float4*)(w1r + k);
        float4 wb = *(const float4*)(w2r + k);
        d1 += xv.x * wa.x + xv.y * wa.y + xv.z * wa.z + xv.w * wa.w;
        d2 += xv.x * wb.x + xv.y * wb.y + xv.z * wb.z + xv.w * wb.w;
    }
    int grow = row0 + r;
    float wh1 = d1 + b1[h];
    float wh2 = d2 + b2[h];
    Wh1[(size_t)grow * H + h] = wh1;
    Wh2[(size_t)grow * H + h] = wh2;

    float v1 = wh1 * a1[h];
    float v2 = wh2 * a2[h];
#pragma unroll
    for (int m = 16; m >= 1; m >>= 1) { v1 += __shfl_xor(v1, m); v2 += __shfl_xor(v2, m); }
    if (h == 0) { s1[grow] = v1; s2[grow] = v2; }
}

// ---------------------------------------------------------------------------
// K1b: global max of s1, s2 -> M[0], M[1]
// ---------------------------------------------------------------------------
__global__ __launch_bounds__(256) void k1b_max(
    const float* __restrict__ s1, const float* __restrict__ s2, float* __restrict__ M)
{
    int tid = threadIdx.x;
    float m1 = -1e30f, m2 = -1e30f;
    for (int i = tid; i < N_NODES; i += 256) {
        m1 = fmaxf(m1, s1[i]);
        m2 = fmaxf(m2, s2[i]);
    }
#pragma unroll
    for (int m = 32; m >= 1; m >>= 1) {
        m1 = fmaxf(m1, __shfl_xor(m1, m));
        m2 = fmaxf(m2, __shfl_xor(m2, m));
    }
    __shared__ float red[8];
    if ((tid & 63) == 0) { red[(tid >> 6) * 2] = m1; red[(tid >> 6) * 2 + 1] = m2; }
    __syncthreads();
    if (tid == 0) {
        float a = red[0], b = red[1];
        for (int w = 1; w < 4; ++w) { a = fmaxf(a, red[w * 2]); b = fmaxf(b, red[w * 2 + 1]); }
        M[0] = a; M[1] = b;
    }
}

// ---------------------------------------------------------------------------
// K2: attention pass. Per block: 64 rows, j-range = 2048 (jb of 4 splits).
// Writes partial numerator (32) + denominator (1) per (jb,row) -> part[jb][row][33]
// block = 512 threads = 8 waves; each wave handles 8 rows in phase 2.
// ---------------------------------------------------------------------------
template <bool HAS_ADJ>
__global__ __launch_bounds__(512) void k2_attn(
    const float* __restrict__ s, const float* __restrict__ Wh,
    const int* __restrict__ adj, const float* __restrict__ M, int mIdx,
    float* __restrict__ part)
{
    __shared__ float w_lds[64 * 128];     // 32 KB
    __shared__ float wh_lds[128 * H];     // 16 KB
    __shared__ float srow[64];
    __shared__ float crow[64];
    __shared__ float denom[64];

    int tid = threadIdx.x;
    int row0 = blockIdx.x * 64;
    int jb = blockIdx.y;
    int jstart = jb * 2048;

    if (tid < 64) {
        float sv = s[row0 + tid];
        srow[tid] = sv;
        crow[tid] = lrelu(sv + M[mIdx]);
        denom[tid] = 0.f;
    }
    __syncthreads();

    int wave = tid >> 6;
    int lane = tid & 63;
    int h = lane & 31;
    int half = lane >> 5;
    float acc[4] = {0.f, 0.f, 0.f, 0.f};

    for (int jt = 0; jt < 16; ++jt) {
        int j0 = jstart + jt * 128;

        // ---- phase 1a: compute w tile (64 rows x 128 j) + stage Wh tile ----
#pragma unroll
        for (int kk = 0; kk < 4; ++kk) {
            int idx = kk * 512 + tid;
            int r = idx >> 5;
            int jc = (idx & 31) * 4;
            float4 sj = *(const float4*)(s + j0 + jc);
            float sr = srow[r], cr = crow[r];
            float4 wv;
            wv.x = __expf(lrelu(sr + sj.x) - cr);
            wv.y = __expf(lrelu(sr + sj.y) - cr);
            wv.z = __expf(lrelu(sr + sj.z) - cr);
            wv.w = __expf(lrelu(sr + sj.w) - cr);
            if (HAS_ADJ) {
                int4 av = *(const int4*)(adj + (size_t)(row0 + r) * N_NODES + j0 + jc);
                if (av.x == 0) wv.x = 0.f;
                if (av.y == 0) wv.y = 0.f;
                if (av.z == 0) wv.z = 0.f;
                if (av.w == 0) wv.w = 0.f;
            }
            *(float4*)(w_lds + r * 128 + jc) = wv;
        }
        {
            const float4* src = (const float4*)(Wh + (size_t)j0 * H);
            float4* dst = (float4*)wh_lds;
            dst[tid] = src[tid];
            dst[512 + tid] = src[512 + tid];
        }
        __syncthreads();

        // ---- phase 1b: per-row denominator partial over this tile ----
        {
            int r = tid >> 3;
            const float* wr = w_lds + r * 128 + (tid & 7) * 16;
            float sum = 0.f;
#pragma unroll
            for (int k = 0; k < 16; ++k) sum += wr[k];
            sum += __shfl_xor(sum, 1);
            sum += __shfl_xor(sum, 2);
            sum += __shfl_xor(sum, 4);
            if ((tid & 7) == 0) denom[r] += sum;
        }
        __syncthreads();

        // ---- phase 2: acc[row][h] += sum_j w[row][j] * Wh[j][h] ----
#pragma unroll
        for (int chunk = 0; chunk < 128; chunk += 16) {
            float whr[16];
#pragma unroll
            for (int k = 0; k < 16; ++k) whr[k] = wh_lds[(chunk + k) * H + h];
#pragma unroll
            for (int pr = 0; pr < 4; ++pr) {
                int r = wave * 8 + pr * 2 + half;
                const float4* wp = (const float4*)(w_lds + r * 128 + chunk);
                float4 w0 = wp[0], w1 = wp[1], w2 = wp[2], w3 = wp[3];
                float a = acc[pr];
                a += w0.x * whr[0];  a += w0.y * whr[1];  a += w0.z * whr[2];  a += w0.w * whr[3];
                a += w1.x * whr[4];  a += w1.y * whr[5];  a += w1.z * whr[6];  a += w1.w * whr[7];
                a += w2.x * whr[8];  a += w2.y * whr[9];  a += w2.z * whr[10]; a += w2.w * whr[11];
                a += w3.x * whr[12]; a += w3.y * whr[13]; a += w3.z * whr[14]; a += w3.w * whr[15];
                acc[pr] = a;
            }
        }
        __syncthreads();
    }

#pragma unroll
    for (int pr = 0; pr < 4; ++pr) {
        int r = wave * 8 + pr * 2 + half;
        int grow = row0 + r;
        size_t base = ((size_t)jb * N_NODES + grow) * 33;
        part[base + h] = acc[pr];
        if (h == 0) part[base + 32] = denom[r];
    }
}

// ---------------------------------------------------------------------------
// K2b: reduce 4 j-split partials -> z = sigmoid(num/den)
// ---------------------------------------------------------------------------
__global__ __launch_bounds__(256) void k2b_reduce(
    const float* __restrict__ part, float* __restrict__ z)
{
    int g = blockIdx.x * 256 + threadIdx.x;
    int row = g >> 5, h = g & 31;
    float num = 0.f, den = 0.f;
#pragma unroll
    for (int jb = 0; jb < 4; ++jb) {
        size_t base = ((size_t)jb * N_NODES + row) * 33;
        num += part[base + h];
        den += part[base + 32];
    }
    float v = den > 0.f ? num / den : 0.f;
    z[g] = sigmoidf_(v);
}

// ---------------------------------------------------------------------------
// K3: per-block partial sums of tanh(z@Ws^T + Ws_b + b_sem)@q for both paths
// ---------------------------------------------------------------------------
__global__ __launch_bounds__(256) void k3_score(
    const float* __restrict__ z1, const float* __restrict__ z2,
    const float* __restrict__ Wsw, const float* __restrict__ Wsb,
    const float* __restrict__ bsem, const float* __restrict__ q,
    float* __restrict__ partial)
{
    __shared__ float zl[256];
    __shared__ float rowsum[8];
    int tid = threadIdx.x;
    int row0 = blockIdx.x * 8;
    int r = tid >> 5, h = tid & 31;
    const float* zs[2] = {z1, z2};

    for (int p = 0; p < 2; ++p) {
        zl[tid] = zs[p][(size_t)row0 * H + tid];
        __syncthreads();
        float d = 0.f;
        const float* wr = Wsw + h * H;
        const float* zr = zl + r * H;
#pragma unroll
        for (int k = 0; k < H; ++k) d += zr[k] * wr[k];
        float val = tanh_fast(d + Wsb[h] + bsem[h]) * q[h];
#pragma unroll
        for (int m = 16; m >= 1; m >>= 1) val += __shfl_xor(val, m);
        if (h == 0) rowsum[r] = val;
        __syncthreads();
        if (tid == 0) {
            float sum = 0.f;
#pragma unroll
            for (int i = 0; i < 8; ++i) sum += rowsum[i];
            partial[p * 1024 + blockIdx.x] = sum;
        }
        __syncthreads();
    }
}

// ---------------------------------------------------------------------------
// K3b: sum partials -> path scores -> beta (softmax over 2)
// ---------------------------------------------------------------------------
__global__ __launch_bounds__(256) void k3b_beta(
    const float* __restrict__ partial, float* __restrict__ beta)
{
    int tid = threadIdx.x;
    float s1 = 0.f, s2 = 0.f;
    for (int i = tid; i < 1024; i += 256) { s1 += partial[i]; s2 += partial[1024 + i]; }
#pragma unroll
    for (int m = 32; m >= 1; m >>= 1) { s1 += __shfl_xor(s1, m); s2 += __shfl_xor(s2, m); }
    __shared__ float red[8];
    if ((tid & 63) == 0) { red[(tid >> 6) * 2] = s1; red[(tid >> 6) * 2 + 1] = s2; }
    __syncthreads();
    if (tid == 0) {
        float a = red[0] + red[2] + red[4] + red[6];
        float b = red[1] + red[3] + red[5] + red[7];
        a /= (float)N_NODES;
        b /= (float)N_NODES;
        float mx = fmaxf(a, b);
        float e1 = __expf(a - mx), e2 = __expf(b - mx);
        float inv = 1.f / (e1 + e2);
        beta[0] = e1 * inv;
        beta[1] = e2 * inv;
    }
}

// ---------------------------------------------------------------------------
// K4: z_final = b0*z1 + b1*z2 ; logits = z_final @ cls_w^T + cls_b
// out = [z_final (8192*32) | logits (8192*2)]
// ---------------------------------------------------------------------------
__global__ __launch_bounds__(256) void k4_final(
    const float* __restrict__ z1, const float* __restrict__ z2,
    const float* __restrict__ beta,
    const float* __restrict__ clsw, const float* __restrict__ clsb,
    float* __restrict__ out)
{
    int tid = threadIdx.x;
    int row0 = blockIdx.x * 8;
    int r = tid >> 5, h = tid & 31;
    int grow = row0 + r;
    size_t gi = (size_t)grow * H + h;
    float b0 = beta[0], b1 = beta[1];
    float zf = b0 * z1[gi] + b1 * z2[gi];
    out[gi] = zf;
    float p0 = zf * clsw[h];
    float p1 = zf * clsw[H + h];
#pragma unroll
    for (int m = 16; m >= 1; m >>= 1) { p0 += __shfl_xor(p0, m); p1 += __shfl_xor(p1, m); }
    if (h == 0) {
        out[(size_t)N_NODES * H + (size_t)grow * 2]     = p0 + clsb[0];
        out[(size_t)N_NODES * H + (size_t)grow * 2 + 1] = p1 + clsb[1];
    }
}

extern "C" void kernel_launch(void* const* d_in, const int* in_sizes, int n_in,
                              void* d_out, int out_size, void* d_ws, size_t ws_size,
                              hipStream_t stream)
{
    const float* x    = (const float*)d_in[0];
    const float* W1   = (const float*)d_in[1];
    const float* b1   = (const float*)d_in[2];
    const float* a1   = (const float*)d_in[3];
    const float* W2   = (const float*)d_in[4];
    const float* b2   = (const float*)d_in[5];
    const float* a2   = (const float*)d_in[6];
    const float* q    = (const float*)d_in[7];
    const float* Wsw  = (const float*)d_in[8];
    const float* Wsb  = (const float*)d_in[9];
    const float* bsem = (const float*)d_in[10];
    const float* clsw = (const float*)d_in[11];
    const float* clsb = (const float*)d_in[12];
    const int*   adj  = (const int*)d_in[13];
    // d_in[14] = mg_adj : unused by the reference computation

    float* ws = (float*)d_ws;
    float* Wh1     = ws;                       // 262144
    float* Wh2     = Wh1 + N_NODES * H;        // 262144
    float* s1      = Wh2 + N_NODES * H;        // 8192
    float* s2      = s1 + N_NODES;             // 8192
    float* M       = s2 + N_NODES;             // 8 (2 used)
    float* beta    = M + 8;                    // 8 (2 used)
    float* partial = beta + 8;                 // 2048
    float* z1      = partial + 2048;           // 262144
    float* z2      = z1 + N_NODES * H;         // 262144
    float* part    = z2 + N_NODES * H;         // 4*8192*33 = 1081344

    float* out = (float*)d_out;

    hipLaunchKernelGGL(k1_wh_s, dim3(1024), dim3(256), 0, stream,
                       x, W1, b1, a1, W2, b2, a2, Wh1, Wh2, s1, s2);
    hipLaunchKernelGGL(k1b_max, dim3(1), dim3(256), 0, stream, s1, s2, M);

    hipLaunchKernelGGL((k2_attn<true>), dim3(128, 4), dim3(512), 0, stream,
                       s1, Wh1, adj, M, 0, part);
    hipLaunchKernelGGL(k2b_reduce, dim3(1024), dim3(256), 0, stream, part, z1);

    hipLaunchKernelGGL((k2_attn<false>), dim3(128, 4), dim3(512), 0, stream,
                       s2, Wh2, (const int*)nullptr, M, 1, part);
    hipLaunchKernelGGL(k2b_reduce, dim3(1024), dim3(256), 0, stream, part, z2);

    hipLaunchKernelGGL(k3_score, dim3(1024), dim3(256), 0, stream,
                       z1, z2, Wsw, Wsb, bsem, q, partial);
    hipLaunchKernelGGL(k3b_beta, dim3(1), dim3(256), 0, stream, partial, beta);
    hipLaunchKernelGGL(k4_final, dim3(1024), dim3(256), 0, stream,
                       z1, z2, beta, clsw, clsb, out);
}

// Round 3
// 180.838 us; speedup vs baseline: 2.5931x; 2.5931x over previous
//
#include <hip/hip_runtime.h>
#include <cstdint>
#include <cstddef>

#define N_NODES 8192
#define IN_DIM 128
#define H 32

typedef __attribute__((ext_vector_type(8))) short short8;
typedef __attribute__((ext_vector_type(4))) float f32x4;
typedef __attribute__((ext_vector_type(4))) unsigned short u16x4;

__device__ __forceinline__ float lrelu(float x) { return x >= 0.0f ? x : 0.2f * x; }
__device__ __forceinline__ float sigmoidf_(float x) { return 1.0f / (1.0f + __expf(-x)); }
__device__ __forceinline__ float tanh_fast(float x) { return 1.0f - 2.0f / (1.0f + __expf(2.0f * x)); }
__device__ __forceinline__ unsigned short f2bf(float f) {
    unsigned u = __float_as_uint(f);
    unsigned r = (u + 0x7fffu + ((u >> 16) & 1u)) >> 16;
    return (unsigned short)r;
}

// ---------------------------------------------------------------------------
// K1: Wh = x@W^T + b for both paths; writes WhT in bf16 (H x N) + s = Wh@a
// block = 256 threads = 8 rows x 32 h-lanes
// ---------------------------------------------------------------------------
__global__ __launch_bounds__(256) void k1_wh_s(
    const float* __restrict__ x,
    const float* __restrict__ W1, const float* __restrict__ b1, const float* __restrict__ a1,
    const float* __restrict__ W2, const float* __restrict__ b2, const float* __restrict__ a2,
    unsigned short* __restrict__ WhT1, unsigned short* __restrict__ WhT2,
    float* __restrict__ s1, float* __restrict__ s2)
{
    __shared__ float xl[8 * IN_DIM];
    __shared__ __align__(16) unsigned short t1[32][8];
    __shared__ __align__(16) unsigned short t2[32][8];
    int tid = threadIdx.x;
    int row0 = blockIdx.x * 8;

    ((float4*)xl)[tid] = ((const float4*)(x + (size_t)row0 * IN_DIM))[tid];
    __syncthreads();

    int r = tid >> 5, h = tid & 31;
    const float* xr = xl + r * IN_DIM;
    const float* w1r = W1 + h * IN_DIM;
    const float* w2r = W2 + h * IN_DIM;
    float d1 = 0.f, d2 = 0.f;
#pragma unroll 8
    for (int k = 0; k < IN_DIM; k += 4) {
        float4 xv = *(const float4*)(xr + k);
        float4 wa = *(const float4*)(w1r + k);
        float4 wb = *(const float4*)(w2r + k);
        d1 += xv.x * wa.x + xv.y * wa.y + xv.z * wa.z + xv.w * wa.w;
        d2 += xv.x * wb.x + xv.y * wb.y + xv.z * wb.z + xv.w * wb.w;
    }
    int grow = row0 + r;
    float wh1 = d1 + b1[h];
    float wh2 = d2 + b2[h];
    t1[h][r] = f2bf(wh1);
    t2[h][r] = f2bf(wh2);

    float v1 = wh1 * a1[h];
    float v2 = wh2 * a2[h];
#pragma unroll
    for (int m = 16; m >= 1; m >>= 1) { v1 += __shfl_xor(v1, m); v2 += __shfl_xor(v2, m); }
    if (h == 0) { s1[grow] = v1; s2[grow] = v2; }
    __syncthreads();

    if (tid < 32) {
        *(short8*)(WhT1 + (size_t)tid * N_NODES + row0) = *(const short8*)&t1[tid][0];
    } else if (tid < 64) {
        int hh = tid - 32;
        *(short8*)(WhT2 + (size_t)hh * N_NODES + row0) = *(const short8*)&t2[hh][0];
    }
}

// ---------------------------------------------------------------------------
// K1b: global max of s1, s2 -> M[0], M[1]
// ---------------------------------------------------------------------------
__global__ __launch_bounds__(256) void k1b_max(
    const float* __restrict__ s1, const float* __restrict__ s2, float* __restrict__ M)
{
    int tid = threadIdx.x;
    float m1 = -1e30f, m2 = -1e30f;
    for (int i = tid; i < N_NODES; i += 256) {
        m1 = fmaxf(m1, s1[i]);
        m2 = fmaxf(m2, s2[i]);
    }
#pragma unroll
    for (int m = 32; m >= 1; m >>= 1) {
        m1 = fmaxf(m1, __shfl_xor(m1, m));
        m2 = fmaxf(m2, __shfl_xor(m2, m));
    }
    __shared__ float red[8];
    if ((tid & 63) == 0) { red[(tid >> 6) * 2] = m1; red[(tid >> 6) * 2 + 1] = m2; }
    __syncthreads();
    if (tid == 0) {
        float a = red[0], b = red[1];
        for (int w = 1; w < 4; ++w) { a = fmaxf(a, red[w * 2]); b = fmaxf(b, red[w * 2 + 1]); }
        M[0] = a; M[1] = b;
    }
}

// ---------------------------------------------------------------------------
// K2: MFMA attention pass. Block: 64 rows x 2048 j (jb in {0..3}).
// 512 threads = 8 waves; wave w -> row-group (w>>1)*16, h-group (w&1)*16.
// w tile (bf16, swizzled) + WhT tile (bf16, swizzled) in LDS; 4 MFMA per tile.
// Denominator folded into w-gen via half-wave shuffle reduce.
// part[jb][row][0..31]=num, [32]=den
// ---------------------------------------------------------------------------
template <bool HAS_ADJ>
__global__ __launch_bounds__(512) void k2_attn(
    const float* __restrict__ s, const unsigned short* __restrict__ WhT,
    const int* __restrict__ adj, const float* __restrict__ M, int mIdx,
    float* __restrict__ part)
{
    __shared__ unsigned short w_lds[64 * 128];   // 16 KB, rows of 256 B, XOR-swizzled
    __shared__ unsigned short whT[32 * 128];     // 8 KB,  rows of 256 B, XOR-swizzled
    __shared__ float srow[64];
    __shared__ float crow[64];
    __shared__ float denom[64];

    int tid = threadIdx.x;
    int row0 = blockIdx.x * 64;
    int jb = blockIdx.y;
    int jstart = jb * 2048;

    if (tid < 64) {
        float sv = s[row0 + tid];
        srow[tid] = sv;
        crow[tid] = lrelu(sv + M[mIdx]);
        denom[tid] = 0.f;
    }
    __syncthreads();

    int wave = tid >> 6;
    int lane = tid & 63;
    int rg = wave >> 1;        // row group 0..3
    int hg = wave & 1;         // h group 0..1
    int grp = lane >> 4;       // k-group 0..3

    int arow = rg * 16 + (lane & 15);
    int aswz = (arow & 7) << 4;
    int a_noswz = arow * 256 + grp * 16;
    int brow = hg * 16 + (lane & 15);
    int bswz = (brow & 7) << 4;
    int b_noswz = brow * 256 + grp * 16;

    int sh = tid >> 4, sc = tid & 15;   // whT staging coords
    int s_byte = (sh * 256 + sc * 16) ^ ((sh & 7) << 4);
    const unsigned short* whT_src = WhT + (size_t)sh * N_NODES + sc * 8;

    f32x4 acc = {0.f, 0.f, 0.f, 0.f};

    for (int jt = 0; jt < 16; ++jt) {
        int j0 = jstart + jt * 128;

        // stage WhT tile (issue global load early)
        short8 whv = *(const short8*)(whT_src + j0);
        *(short8*)((char*)whT + s_byte) = whv;

        // w tile: 64 rows x 128 j, 4 elems/thread/iter
#pragma unroll
        for (int kk = 0; kk < 4; ++kk) {
            int idx = kk * 512 + tid;
            int r = idx >> 5;
            int jc = (idx & 31) * 4;
            float4 sj = *(const float4*)(s + j0 + jc);
            float sr = srow[r], cr = crow[r];
            float4 wv;
            wv.x = __expf(lrelu(sr + sj.x) - cr);
            wv.y = __expf(lrelu(sr + sj.y) - cr);
            wv.z = __expf(lrelu(sr + sj.z) - cr);
            wv.w = __expf(lrelu(sr + sj.w) - cr);
            if (HAS_ADJ) {
                int4 av = *(const int4*)(adj + (size_t)(row0 + r) * N_NODES + j0 + jc);
                if (av.x == 0) wv.x = 0.f;
                if (av.y == 0) wv.y = 0.f;
                if (av.z == 0) wv.z = 0.f;
                if (av.w == 0) wv.w = 0.f;
            }
            // denominator partial: reduce across the 32 lanes sharing this row
            float sum4 = wv.x + wv.y + wv.z + wv.w;
            sum4 += __shfl_xor(sum4, 1);
            sum4 += __shfl_xor(sum4, 2);
            sum4 += __shfl_xor(sum4, 4);
            sum4 += __shfl_xor(sum4, 8);
            sum4 += __shfl_xor(sum4, 16);
            if ((tid & 31) == 0) denom[r] += sum4;

            u16x4 wp;
            wp.x = f2bf(wv.x); wp.y = f2bf(wv.y); wp.z = f2bf(wv.z); wp.w = f2bf(wv.w);
            int byte = (r * 256 + jc * 2) ^ ((r & 7) << 4);
            *(u16x4*)((char*)w_lds + byte) = wp;
        }
        __syncthreads();

        // MFMA: 4 K-steps of 32 over this 128-j tile
#pragma unroll
        for (int ks = 0; ks < 4; ++ks) {
            short8 a = *(const short8*)((const char*)w_lds + ((a_noswz + ks * 64) ^ aswz));
            short8 b = *(const short8*)((const char*)whT + ((b_noswz + ks * 64) ^ bswz));
            acc = __builtin_amdgcn_mfma_f32_16x16x32_bf16(a, b, acc, 0, 0, 0);
        }
        __syncthreads();
    }

    // write out: C/D layout col=lane&15 (h), row=(lane>>4)*4+reg (m)
#pragma unroll
    for (int reg = 0; reg < 4; ++reg) {
        int grow = row0 + rg * 16 + grp * 4 + reg;
        part[((size_t)jb * N_NODES + grow) * 33 + hg * 16 + (lane & 15)] = acc[reg];
    }
    if (tid < 64) {
        part[((size_t)jb * N_NODES + row0 + tid) * 33 + 32] = denom[tid];
    }
}

// ---------------------------------------------------------------------------
// K2b: reduce 4 j-split partials -> z = sigmoid(num/den)
// ---------------------------------------------------------------------------
__global__ __launch_bounds__(256) void k2b_reduce(
    const float* __restrict__ part, float* __restrict__ z)
{
    int g = blockIdx.x * 256 + threadIdx.x;
    int row = g >> 5, h = g & 31;
    float num = 0.f, den = 0.f;
#pragma unroll
    for (int jb = 0; jb < 4; ++jb) {
        size_t base = ((size_t)jb * N_NODES + row) * 33;
        num += part[base + h];
        den += part[base + 32];
    }
    float v = den > 0.f ? num / den : 0.f;
    z[g] = sigmoidf_(v);
}

// ---------------------------------------------------------------------------
// K3: per-block partial sums of tanh(z@Ws^T + Ws_b + b_sem)@q for both paths
// ---------------------------------------------------------------------------
__global__ __launch_bounds__(256) void k3_score(
    const float* __restrict__ z1, const float* __restrict__ z2,
    const float* __restrict__ Wsw, const float* __restrict__ Wsb,
    const float* __restrict__ bsem, const float* __restrict__ q,
    float* __restrict__ partial)
{
    __shared__ float zl[256];
    __shared__ float rowsum[8];
    int tid = threadIdx.x;
    int row0 = blockIdx.x * 8;
    int r = tid >> 5, h = tid & 31;
    const float* zs[2] = {z1, z2};

    for (int p = 0; p < 2; ++p) {
        zl[tid] = zs[p][(size_t)row0 * H + tid];
        __syncthreads();
        float d = 0.f;
        const float* wr = Wsw + h * H;
        const float* zr = zl + r * H;
#pragma unroll
        for (int k = 0; k < H; ++k) d += zr[k] * wr[k];
        float val = tanh_fast(d + Wsb[h] + bsem[h]) * q[h];
#pragma unroll
        for (int m = 16; m >= 1; m >>= 1) val += __shfl_xor(val, m);
        if (h == 0) rowsum[r] = val;
        __syncthreads();
        if (tid == 0) {
            float sum = 0.f;
#pragma unroll
            for (int i = 0; i < 8; ++i) sum += rowsum[i];
            partial[p * 1024 + blockIdx.x] = sum;
        }
        __syncthreads();
    }
}

// ---------------------------------------------------------------------------
// K3b: sum partials -> path scores -> beta (softmax over 2)
// ---------------------------------------------------------------------------
__global__ __launch_bounds__(256) void k3b_beta(
    const float* __restrict__ partial, float* __restrict__ beta)
{
    int tid = threadIdx.x;
    float s1 = 0.f, s2 = 0.f;
    for (int i = tid; i < 1024; i += 256) { s1 += partial[i]; s2 += partial[1024 + i]; }
#pragma unroll
    for (int m = 32; m >= 1; m >>= 1) { s1 += __shfl_xor(s1, m); s2 += __shfl_xor(s2, m); }
    __shared__ float red[8];
    if ((tid & 63) == 0) { red[(tid >> 6) * 2] = s1; red[(tid >> 6) * 2 + 1] = s2; }
    __syncthreads();
    if (tid == 0) {
        float a = red[0] + red[2] + red[4] + red[6];
        float b = red[1] + red[3] + red[5] + red[7];
        a /= (float)N_NODES;
        b /= (float)N_NODES;
        float mx = fmaxf(a, b);
        float e1 = __expf(a - mx), e2 = __expf(b - mx);
        float inv = 1.f / (e1 + e2);
        beta[0] = e1 * inv;
        beta[1] = e2 * inv;
    }
}

// ---------------------------------------------------------------------------
// K4: z_final = b0*z1 + b1*z2 ; logits = z_final @ cls_w^T + cls_b
// out = [z_final (8192*32) | logits (8192*2)]
// ---------------------------------------------------------------------------
__global__ __launch_bounds__(256) void k4_final(
    const float* __restrict__ z1, const float* __restrict__ z2,
    const float* __restrict__ beta,
    const float* __restrict__ clsw, const float* __restrict__ clsb,
    float* __restrict__ out)
{
    int tid = threadIdx.x;
    int row0 = blockIdx.x * 8;
    int r = tid >> 5, h = tid & 31;
    int grow = row0 + r;
    size_t gi = (size_t)grow * H + h;
    float b0 = beta[0], b1 = beta[1];
    float zf = b0 * z1[gi] + b1 * z2[gi];
    out[gi] = zf;
    float p0 = zf * clsw[h];
    float p1 = zf * clsw[H + h];
#pragma unroll
    for (int m = 16; m >= 1; m >>= 1) { p0 += __shfl_xor(p0, m); p1 += __shfl_xor(p1, m); }
    if (h == 0) {
        out[(size_t)N_NODES * H + (size_t)grow * 2]     = p0 + clsb[0];
        out[(size_t)N_NODES * H + (size_t)grow * 2 + 1] = p1 + clsb[1];
    }
}

extern "C" void kernel_launch(void* const* d_in, const int* in_sizes, int n_in,
                              void* d_out, int out_size, void* d_ws, size_t ws_size,
                              hipStream_t stream)
{
    const float* x    = (const float*)d_in[0];
    const float* W1   = (const float*)d_in[1];
    const float* b1   = (const float*)d_in[2];
    const float* a1   = (const float*)d_in[3];
    const float* W2   = (const float*)d_in[4];
    const float* b2   = (const float*)d_in[5];
    const float* a2   = (const float*)d_in[6];
    const float* q    = (const float*)d_in[7];
    const float* Wsw  = (const float*)d_in[8];
    const float* Wsb  = (const float*)d_in[9];
    const float* bsem = (const float*)d_in[10];
    const float* clsw = (const float*)d_in[11];
    const float* clsb = (const float*)d_in[12];
    const int*   adj  = (const int*)d_in[13];
    // d_in[14] = mg_adj : unused by the reference computation

    // Workspace layout in FLOAT units. WhT buffers are bf16: N*H = 262144
    // shorts = 131072 floats EACH (the round-2 bug: s1 was placed at +131072,
    // aliasing WhT2 -> NaN).
    float* ws = (float*)d_ws;
    unsigned short* WhT1 = (unsigned short*)ws;            // floats [0, 131072)
    unsigned short* WhT2 = (unsigned short*)(ws + 131072); // floats [131072, 262144)
    float* s1      = ws + 262144;                          // 8192
    float* s2      = s1 + N_NODES;                         // 8192
    float* M       = s2 + N_NODES;                         // 8 (2 used)
    float* beta    = M + 8;                                // 8 (2 used)
    float* partial = beta + 8;                             // 2048
    float* z1      = partial + 2048;                       // 262144
    float* z2      = z1 + N_NODES * H;                     // 262144
    float* part    = z2 + N_NODES * H;                     // 4*8192*33 = 1081344
    // total = 1,886,224 floats ~= 7.5 MB

    float* out = (float*)d_out;

    hipLaunchKernelGGL(k1_wh_s, dim3(1024), dim3(256), 0, stream,
                       x, W1, b1, a1, W2, b2, a2, WhT1, WhT2, s1, s2);
    hipLaunchKernelGGL(k1b_max, dim3(1), dim3(256), 0, stream, s1, s2, M);

    hipLaunchKernelGGL((k2_attn<true>), dim3(128, 4), dim3(512), 0, stream,
                       s1, WhT1, adj, M, 0, part);
    hipLaunchKernelGGL(k2b_reduce, dim3(1024), dim3(256), 0, stream, part, z1);

    hipLaunchKernelGGL((k2_attn<false>), dim3(128, 4), dim3(512), 0, stream,
                       s2, WhT2, (const int*)nullptr, M, 1, part);
    hipLaunchKernelGGL(k2b_reduce, dim3(1024), dim3(256), 0, stream, part, z2);

    hipLaunchKernelGGL(k3_score, dim3(1024), dim3(256), 0, stream,
                       z1, z2, Wsw, Wsb, bsem, q, partial);
    hipLaunchKernelGGL(k3b_beta, dim3(1), dim3(256), 0, stream, partial, beta);
    hipLaunchKernelGGL(k4_final, dim3(1024), dim3(256), 0, stream,
                       z1, z2, beta, clsw, clsb, out);
}

// Round 4
// 160.770 us; speedup vs baseline: 2.9168x; 1.1248x over previous
//
#include <hip/hip_runtime.h>
#include <cstdint>
#include <cstddef>

#define N_NODES 8192
#define IN_DIM 128
#define H 32

typedef __attribute__((ext_vector_type(8))) short short8;
typedef __attribute__((ext_vector_type(4))) float f32x4;
typedef __attribute__((ext_vector_type(4))) unsigned short u16x4;

__device__ __forceinline__ float lrelu(float x) { return x >= 0.0f ? x : 0.2f * x; }
__device__ __forceinline__ float sigmoidf_(float x) { return 1.0f / (1.0f + __expf(-x)); }
__device__ __forceinline__ float tanh_fast(float x) { return 1.0f - 2.0f / (1.0f + __expf(2.0f * x)); }
__device__ __forceinline__ unsigned short f2bf(float f) {
    unsigned u = __float_as_uint(f);
    unsigned r = (u + 0x7fffu + ((u >> 16) & 1u)) >> 16;
    return (unsigned short)r;
}

// ---------------------------------------------------------------------------
// K1: Wh = x@W^T + b for both paths; writes WhT in bf16 (H x N) + s = Wh@a
// ---------------------------------------------------------------------------
__global__ __launch_bounds__(256) void k1_wh_s(
    const float* __restrict__ x,
    const float* __restrict__ W1, const float* __restrict__ b1, const float* __restrict__ a1,
    const float* __restrict__ W2, const float* __restrict__ b2, const float* __restrict__ a2,
    unsigned short* __restrict__ WhT1, unsigned short* __restrict__ WhT2,
    float* __restrict__ s1, float* __restrict__ s2)
{
    __shared__ float xl[8 * IN_DIM];
    __shared__ __align__(16) unsigned short t1[32][8];
    __shared__ __align__(16) unsigned short t2[32][8];
    int tid = threadIdx.x;
    int row0 = blockIdx.x * 8;

    ((float4*)xl)[tid] = ((const float4*)(x + (size_t)row0 * IN_DIM))[tid];
    __syncthreads();

    int r = tid >> 5, h = tid & 31;
    const float* xr = xl + r * IN_DIM;
    const float* w1r = W1 + h * IN_DIM;
    const float* w2r = W2 + h * IN_DIM;
    float d1 = 0.f, d2 = 0.f;
#pragma unroll 8
    for (int k = 0; k < IN_DIM; k += 4) {
        float4 xv = *(const float4*)(xr + k);
        float4 wa = *(const float4*)(w1r + k);
        float4 wb = *(const float4*)(w2r + k);
        d1 += xv.x * wa.x + xv.y * wa.y + xv.z * wa.z + xv.w * wa.w;
        d2 += xv.x * wb.x + xv.y * wb.y + xv.z * wb.z + xv.w * wb.w;
    }
    int grow = row0 + r;
    float wh1 = d1 + b1[h];
    float wh2 = d2 + b2[h];
    t1[h][r] = f2bf(wh1);
    t2[h][r] = f2bf(wh2);

    float v1 = wh1 * a1[h];
    float v2 = wh2 * a2[h];
#pragma unroll
    for (int m = 16; m >= 1; m >>= 1) { v1 += __shfl_xor(v1, m); v2 += __shfl_xor(v2, m); }
    if (h == 0) { s1[grow] = v1; s2[grow] = v2; }
    __syncthreads();

    if (tid < 32) {
        *(short8*)(WhT1 + (size_t)tid * N_NODES + row0) = *(const short8*)&t1[tid][0];
    } else if (tid < 64) {
        int hh = tid - 32;
        *(short8*)(WhT2 + (size_t)hh * N_NODES + row0) = *(const short8*)&t2[hh][0];
    }
}

// ---------------------------------------------------------------------------
// K1b: global max of s1, s2 -> M[0], M[1]
// ---------------------------------------------------------------------------
__global__ __launch_bounds__(256) void k1b_max(
    const float* __restrict__ s1, const float* __restrict__ s2, float* __restrict__ M)
{
    int tid = threadIdx.x;
    float m1 = -1e30f, m2 = -1e30f;
    for (int i = tid; i < N_NODES; i += 256) {
        m1 = fmaxf(m1, s1[i]);
        m2 = fmaxf(m2, s2[i]);
    }
#pragma unroll
    for (int m = 32; m >= 1; m >>= 1) {
        m1 = fmaxf(m1, __shfl_xor(m1, m));
        m2 = fmaxf(m2, __shfl_xor(m2, m));
    }
    __shared__ float red[8];
    if ((tid & 63) == 0) { red[(tid >> 6) * 2] = m1; red[(tid >> 6) * 2 + 1] = m2; }
    __syncthreads();
    if (tid == 0) {
        float a = red[0], b = red[1];
        for (int w = 1; w < 4; ++w) { a = fmaxf(a, red[w * 2]); b = fmaxf(b, red[w * 2 + 1]); }
        M[0] = a; M[1] = b;
    }
}

// ---------------------------------------------------------------------------
// K2 fused: BOTH attention passes in one kernel.
// Block: 64 rows x 2048 j (jb in 0..3). 512 threads = 8 waves.
// Path1 uses adjacency mask (register-prefetched 1 tile ahead); path2 none.
// Denominators: per-thread partials across the whole j-loop (rows kk*16+trh
// are jt-invariant), one shuffle reduce at the end.
// ---------------------------------------------------------------------------
__global__ __launch_bounds__(512) void k2_fused(
    const float* __restrict__ s1g, const float* __restrict__ s2g,
    const unsigned short* __restrict__ WhT1, const unsigned short* __restrict__ WhT2,
    const int* __restrict__ adj, const float* __restrict__ M,
    float* __restrict__ part1, float* __restrict__ part2)
{
    __shared__ unsigned short w1[64 * 128];   // 16 KB, XOR-swizzled
    __shared__ unsigned short w2[64 * 128];   // 16 KB
    __shared__ unsigned short t1[32 * 128];   // 8 KB
    __shared__ unsigned short t2[32 * 128];   // 8 KB
    __shared__ float s1r[64], c1r[64], s2r[64], c2r[64];

    int tid = threadIdx.x;
    int row0 = blockIdx.x * 64;
    int jb = blockIdx.y;
    int jstart = jb * 2048;

    if (tid < 64) {
        float v1 = s1g[row0 + tid], v2 = s2g[row0 + tid];
        s1r[tid] = v1; c1r[tid] = lrelu(v1 + M[0]);
        s2r[tid] = v2; c2r[tid] = lrelu(v2 + M[1]);
    }
    __syncthreads();

    int wave = tid >> 6;
    int lane = tid & 63;
    int rg = wave >> 1;        // row group 0..3
    int hg = wave & 1;         // h group 0..1
    int grp = lane >> 4;       // k-group 0..3

    int arow = rg * 16 + (lane & 15);
    int aswz = (arow & 7) << 4;
    int a_base = arow * 256;
    int brow = hg * 16 + (lane & 15);
    int bswz = (brow & 7) << 4;
    int b_base = brow * 256;

    int sh = tid >> 4, sc = tid & 15;   // WhT staging coords
    int s_byte = (sh * 256 + sc * 16) ^ ((sh & 7) << 4);
    const unsigned short* src1 = WhT1 + (size_t)sh * N_NODES + sc * 8;
    const unsigned short* src2 = WhT2 + (size_t)sh * N_NODES + sc * 8;

    int tcol = (lane & 31) * 4;        // j column within tile (tid&31 == lane&31)
    int trh = tid >> 5;                // 0..15
    const int* adjb = adj + (size_t)row0 * N_NODES + tcol;

    f32x4 acc1 = {0.f, 0.f, 0.f, 0.f};
    f32x4 acc2 = {0.f, 0.f, 0.f, 0.f};
    float l10 = 0.f, l11 = 0.f, l12 = 0.f, l13 = 0.f;
    float l20 = 0.f, l21 = 0.f, l22 = 0.f, l23 = 0.f;

    // adjacency prefetch registers (rows kk*16+trh, cols tcol..tcol+3)
    int4 cA, cB, cC, cD, nA, nB, nC, nD;
    cA = *(const int4*)(adjb + (size_t)(0 * 16 + trh) * N_NODES + jstart);
    cB = *(const int4*)(adjb + (size_t)(1 * 16 + trh) * N_NODES + jstart);
    cC = *(const int4*)(adjb + (size_t)(2 * 16 + trh) * N_NODES + jstart);
    cD = *(const int4*)(adjb + (size_t)(3 * 16 + trh) * N_NODES + jstart);

    for (int jt = 0; jt < 16; ++jt) {
        int j0 = jstart + jt * 128;

        if (jt < 15) {
            int jn = j0 + 128;
            nA = *(const int4*)(adjb + (size_t)(0 * 16 + trh) * N_NODES + jn);
            nB = *(const int4*)(adjb + (size_t)(1 * 16 + trh) * N_NODES + jn);
            nC = *(const int4*)(adjb + (size_t)(2 * 16 + trh) * N_NODES + jn);
            nD = *(const int4*)(adjb + (size_t)(3 * 16 + trh) * N_NODES + jn);
        }

        // stage WhT tiles
        short8 wv1 = *(const short8*)(src1 + j0);
        short8 wv2 = *(const short8*)(src2 + j0);
        *(short8*)((char*)t1 + s_byte) = wv1;
        *(short8*)((char*)t2 + s_byte) = wv2;

        float4 sj1 = *(const float4*)(s1g + j0 + tcol);
        float4 sj2 = *(const float4*)(s2g + j0 + tcol);

#define W_GEN(KK, AV, L1, L2)                                                   \
        {                                                                       \
            int r = KK * 16 + trh;                                              \
            float sr1 = s1r[r], cr1 = c1r[r];                                   \
            float sr2 = s2r[r], cr2 = c2r[r];                                   \
            float4 e1, e2;                                                      \
            e1.x = __expf(lrelu(sr1 + sj1.x) - cr1);                            \
            e1.y = __expf(lrelu(sr1 + sj1.y) - cr1);                            \
            e1.z = __expf(lrelu(sr1 + sj1.z) - cr1);                            \
            e1.w = __expf(lrelu(sr1 + sj1.w) - cr1);                            \
            if (AV.x == 0) e1.x = 0.f;                                          \
            if (AV.y == 0) e1.y = 0.f;                                          \
            if (AV.z == 0) e1.z = 0.f;                                          \
            if (AV.w == 0) e1.w = 0.f;                                          \
            e2.x = __expf(lrelu(sr2 + sj2.x) - cr2);                            \
            e2.y = __expf(lrelu(sr2 + sj2.y) - cr2);                            \
            e2.z = __expf(lrelu(sr2 + sj2.z) - cr2);                            \
            e2.w = __expf(lrelu(sr2 + sj2.w) - cr2);                            \
            L1 += (e1.x + e1.y) + (e1.z + e1.w);                                \
            L2 += (e2.x + e2.y) + (e2.z + e2.w);                                \
            int byte = (r * 256 + tcol * 2) ^ ((r & 7) << 4);                   \
            u16x4 p1, p2;                                                       \
            p1.x = f2bf(e1.x); p1.y = f2bf(e1.y); p1.z = f2bf(e1.z); p1.w = f2bf(e1.w); \
            p2.x = f2bf(e2.x); p2.y = f2bf(e2.y); p2.z = f2bf(e2.z); p2.w = f2bf(e2.w); \
            *(u16x4*)((char*)w1 + byte) = p1;                                   \
            *(u16x4*)((char*)w2 + byte) = p2;                                   \
        }

        W_GEN(0, cA, l10, l20)
        W_GEN(1, cB, l11, l21)
        W_GEN(2, cC, l12, l22)
        W_GEN(3, cD, l13, l23)
#undef W_GEN
        __syncthreads();

#pragma unroll
        for (int ks = 0; ks < 4; ++ks) {
            short8 a1 = *(const short8*)((const char*)w1 + ((a_base + ks * 64 + grp * 16) ^ aswz));
            short8 b1 = *(const short8*)((const char*)t1 + ((b_base + ks * 64 + grp * 16) ^ bswz));
            acc1 = __builtin_amdgcn_mfma_f32_16x16x32_bf16(a1, b1, acc1, 0, 0, 0);
            short8 a2 = *(const short8*)((const char*)w2 + ((a_base + ks * 64 + grp * 16) ^ aswz));
            short8 b2 = *(const short8*)((const char*)t2 + ((b_base + ks * 64 + grp * 16) ^ bswz));
            acc2 = __builtin_amdgcn_mfma_f32_16x16x32_bf16(a2, b2, acc2, 0, 0, 0);
        }
        __syncthreads();

        cA = nA; cB = nB; cC = nC; cD = nD;
    }

    // numerators: C/D layout col=lane&15 (h), row=(lane>>4)*4+reg
#pragma unroll
    for (int reg = 0; reg < 4; ++reg) {
        int grow = row0 + rg * 16 + grp * 4 + reg;
        size_t base = ((size_t)jb * N_NODES + grow) * 33 + hg * 16 + (lane & 15);
        part1[base] = acc1[reg];
        part2[base] = acc2[reg];
    }

    // denominators: reduce each per-thread partial across its 32-lane row group
#define DEN(KK, D1, D2)                                                         \
    {                                                                           \
        float d1 = D1, d2 = D2;                                                 \
        d1 += __shfl_xor(d1, 1);  d2 += __shfl_xor(d2, 1);                      \
        d1 += __shfl_xor(d1, 2);  d2 += __shfl_xor(d2, 2);                      \
        d1 += __shfl_xor(d1, 4);  d2 += __shfl_xor(d2, 4);                      \
        d1 += __shfl_xor(d1, 8);  d2 += __shfl_xor(d2, 8);                      \
        d1 += __shfl_xor(d1, 16); d2 += __shfl_xor(d2, 16);                     \
        if ((tid & 31) == 0) {                                                  \
            int r = KK * 16 + trh;                                              \
            size_t base = ((size_t)jb * N_NODES + row0 + r) * 33 + 32;          \
            part1[base] = d1;                                                   \
            part2[base] = d2;                                                   \
        }                                                                       \
    }
    DEN(0, l10, l20)
    DEN(1, l11, l21)
    DEN(2, l12, l22)
    DEN(3, l13, l23)
#undef DEN
}

// ---------------------------------------------------------------------------
// K2b3: reduce j-split partials -> z = sigmoid(num/den) for both paths,
// then the k3 semantic-score block partials (fused; z stays in LDS).
// grid 1024 x 256; block = 8 rows x 32 h.
// ---------------------------------------------------------------------------
__global__ __launch_bounds__(256) void k2b3(
    const float* __restrict__ part1, const float* __restrict__ part2,
    const float* __restrict__ Wsw, const float* __restrict__ Wsb,
    const float* __restrict__ bsem, const float* __restrict__ q,
    float* __restrict__ z1, float* __restrict__ z2, float* __restrict__ partial)
{
    __shared__ float zl1[256], zl2[256];
    __shared__ float rowsum[8];
    int tid = threadIdx.x;
    int row0 = blockIdx.x * 8;
    int r = tid >> 5, h = tid & 31;
    int row = row0 + r;

    float n1 = 0.f, d1 = 0.f, n2 = 0.f, d2 = 0.f;
#pragma unroll
    for (int jb = 0; jb < 4; ++jb) {
        size_t base = ((size_t)jb * N_NODES + row) * 33;
        n1 += part1[base + h]; d1 += part1[base + 32];
        n2 += part2[base + h]; d2 += part2[base + 32];
    }
    float z1v = sigmoidf_(d1 > 0.f ? n1 / d1 : 0.f);
    float z2v = sigmoidf_(d2 > 0.f ? n2 / d2 : 0.f);
    size_t gi = (size_t)row * H + h;
    z1[gi] = z1v;
    z2[gi] = z2v;
    zl1[tid] = z1v;
    zl2[tid] = z2v;
    __syncthreads();

    const float* wr = Wsw + h * H;
    for (int p = 0; p < 2; ++p) {
        const float* zl = p ? zl2 : zl1;
        float d = 0.f;
        const float* zr = zl + r * H;
#pragma unroll
        for (int k = 0; k < H; ++k) d += zr[k] * wr[k];
        float val = tanh_fast(d + Wsb[h] + bsem[h]) * q[h];
#pragma unroll
        for (int m = 16; m >= 1; m >>= 1) val += __shfl_xor(val, m);
        if (h == 0) rowsum[r] = val;
        __syncthreads();
        if (tid == 0) {
            float s = 0.f;
#pragma unroll
            for (int i = 0; i < 8; ++i) s += rowsum[i];
            partial[p * 1024 + blockIdx.x] = s;
        }
        __syncthreads();
    }
}

// ---------------------------------------------------------------------------
// K3b: sum partials -> path scores -> beta (softmax over 2)
// ---------------------------------------------------------------------------
__global__ __launch_bounds__(256) void k3b_beta(
    const float* __restrict__ partial, float* __restrict__ beta)
{
    int tid = threadIdx.x;
    float s1 = 0.f, s2 = 0.f;
    for (int i = tid; i < 1024; i += 256) { s1 += partial[i]; s2 += partial[1024 + i]; }
#pragma unroll
    for (int m = 32; m >= 1; m >>= 1) { s1 += __shfl_xor(s1, m); s2 += __shfl_xor(s2, m); }
    __shared__ float red[8];
    if ((tid & 63) == 0) { red[(tid >> 6) * 2] = s1; red[(tid >> 6) * 2 + 1] = s2; }
    __syncthreads();
    if (tid == 0) {
        float a = red[0] + red[2] + red[4] + red[6];
        float b = red[1] + red[3] + red[5] + red[7];
        a /= (float)N_NODES;
        b /= (float)N_NODES;
        float mx = fmaxf(a, b);
        float e1 = __expf(a - mx), e2 = __expf(b - mx);
        float inv = 1.f / (e1 + e2);
        beta[0] = e1 * inv;
        beta[1] = e2 * inv;
    }
}

// ---------------------------------------------------------------------------
// K4: z_final = b0*z1 + b1*z2 ; logits = z_final @ cls_w^T + cls_b
// out = [z_final (8192*32) | logits (8192*2)]
// ---------------------------------------------------------------------------
__global__ __launch_bounds__(256) void k4_final(
    const float* __restrict__ z1, const float* __restrict__ z2,
    const float* __restrict__ beta,
    const float* __restrict__ clsw, const float* __restrict__ clsb,
    float* __restrict__ out)
{
    int tid = threadIdx.x;
    int row0 = blockIdx.x * 8;
    int r = tid >> 5, h = tid & 31;
    int grow = row0 + r;
    size_t gi = (size_t)grow * H + h;
    float b0 = beta[0], b1 = beta[1];
    float zf = b0 * z1[gi] + b1 * z2[gi];
    out[gi] = zf;
    float p0 = zf * clsw[h];
    float p1 = zf * clsw[H + h];
#pragma unroll
    for (int m = 16; m >= 1; m >>= 1) { p0 += __shfl_xor(p0, m); p1 += __shfl_xor(p1, m); }
    if (h == 0) {
        out[(size_t)N_NODES * H + (size_t)grow * 2]     = p0 + clsb[0];
        out[(size_t)N_NODES * H + (size_t)grow * 2 + 1] = p1 + clsb[1];
    }
}

extern "C" void kernel_launch(void* const* d_in, const int* in_sizes, int n_in,
                              void* d_out, int out_size, void* d_ws, size_t ws_size,
                              hipStream_t stream)
{
    const float* x    = (const float*)d_in[0];
    const float* W1   = (const float*)d_in[1];
    const float* b1   = (const float*)d_in[2];
    const float* a1   = (const float*)d_in[3];
    const float* W2   = (const float*)d_in[4];
    const float* b2   = (const float*)d_in[5];
    const float* a2   = (const float*)d_in[6];
    const float* q    = (const float*)d_in[7];
    const float* Wsw  = (const float*)d_in[8];
    const float* Wsb  = (const float*)d_in[9];
    const float* bsem = (const float*)d_in[10];
    const float* clsw = (const float*)d_in[11];
    const float* clsb = (const float*)d_in[12];
    const int*   adj  = (const int*)d_in[13];
    // d_in[14] = mg_adj : unused by the reference computation

    // Workspace layout in FLOAT units (WhT buffers are bf16: N*H shorts =
    // 131072 floats EACH). d_ws is ~1 GB (poison fill shows 1.07e9 B) —
    // 12 MB layout is safe.
    float* ws = (float*)d_ws;
    unsigned short* WhT1 = (unsigned short*)ws;            // floats [0, 131072)
    unsigned short* WhT2 = (unsigned short*)(ws + 131072); // floats [131072, 262144)
    float* s1      = ws + 262144;                          // 8192
    float* s2      = s1 + N_NODES;                         // 8192
    float* M       = s2 + N_NODES;                         // 8 (2 used)
    float* beta    = M + 8;                                // 8 (2 used)
    float* partial = beta + 8;                             // 2048 (2 paths x 1024)
    float* z1      = partial + 2048;                       // 262144
    float* z2      = z1 + N_NODES * H;                     // 262144
    float* part1   = z2 + N_NODES * H;                     // 4*8192*33 = 1081344
    float* part2   = part1 + 4 * N_NODES * 33;             // 1081344
    // total ~= 2,967,568 floats ~= 11.9 MB

    float* out = (float*)d_out;

    hipLaunchKernelGGL(k1_wh_s, dim3(1024), dim3(256), 0, stream,
                       x, W1, b1, a1, W2, b2, a2, WhT1, WhT2, s1, s2);
    hipLaunchKernelGGL(k1b_max, dim3(1), dim3(256), 0, stream, s1, s2, M);

    hipLaunchKernelGGL(k2_fused, dim3(128, 4), dim3(512), 0, stream,
                       s1, s2, WhT1, WhT2, adj, M, part1, part2);

    hipLaunchKernelGGL(k2b3, dim3(1024), dim3(256), 0, stream,
                       part1, part2, Wsw, Wsb, bsem, q, z1, z2, partial);

    hipLaunchKernelGGL(k3b_beta, dim3(1), dim3(256), 0, stream, partial, beta);
    hipLaunchKernelGGL(k4_final, dim3(1024), dim3(256), 0, stream,
                       z1, z2, beta, clsw, clsb, out);
}

// Round 5
// 151.420 us; speedup vs baseline: 3.0969x; 1.0618x over previous
//
#include <hip/hip_runtime.h>
#include <cstdint>
#include <cstddef>

#define N_NODES 8192
#define IN_DIM 128
#define H 32
#define KB 8192          // path-2 buckets
#define NCH 66           // 32 E*Wh + 32 F*Wh + E + F channels

typedef __attribute__((ext_vector_type(8))) short short8;
typedef __attribute__((ext_vector_type(4))) float f32x4;
typedef __attribute__((ext_vector_type(4))) unsigned short u16x4;

__device__ __forceinline__ float lrelu(float x) { return x >= 0.0f ? x : 0.2f * x; }
__device__ __forceinline__ float sigmoidf_(float x) { return 1.0f / (1.0f + __expf(-x)); }
__device__ __forceinline__ float tanh_fast(float x) { return 1.0f - 2.0f / (1.0f + __expf(2.0f * x)); }
__device__ __forceinline__ unsigned short f2bf(float f) {
    unsigned u = __float_as_uint(f);
    unsigned r = (u + 0x7fffu + ((u >> 16) & 1u)) >> 16;
    return (unsigned short)r;
}

// ---------------------------------------------------------------------------
// K1: Wh = x@W^T + b for both paths. Path1 -> WhT1 bf16 (H x N) for MFMA.
// Path2 -> Wh2f f32 row-major (N x H) for the bucket pipeline. s = Wh@a.
// ---------------------------------------------------------------------------
__global__ __launch_bounds__(256) void k1_wh_s(
    const float* __restrict__ x,
    const float* __restrict__ W1, const float* __restrict__ b1, const float* __restrict__ a1,
    const float* __restrict__ W2, const float* __restrict__ b2, const float* __restrict__ a2,
    unsigned short* __restrict__ WhT1, float* __restrict__ Wh2f,
    float* __restrict__ s1, float* __restrict__ s2)
{
    __shared__ float xl[8 * IN_DIM];
    __shared__ __align__(16) unsigned short t1[32][8];
    int tid = threadIdx.x;
    int row0 = blockIdx.x * 8;

    ((float4*)xl)[tid] = ((const float4*)(x + (size_t)row0 * IN_DIM))[tid];
    __syncthreads();

    int r = tid >> 5, h = tid & 31;
    const float* xr = xl + r * IN_DIM;
    const float* w1r = W1 + h * IN_DIM;
    const float* w2r = W2 + h * IN_DIM;
    float d1 = 0.f, d2 = 0.f;
#pragma unroll 8
    for (int k = 0; k < IN_DIM; k += 4) {
        float4 xv = *(const float4*)(xr + k);
        float4 wa = *(const float4*)(w1r + k);
        float4 wb = *(const float4*)(w2r + k);
        d1 += xv.x * wa.x + xv.y * wa.y + xv.z * wa.z + xv.w * wa.w;
        d2 += xv.x * wb.x + xv.y * wb.y + xv.z * wb.z + xv.w * wb.w;
    }
    int grow = row0 + r;
    float wh1 = d1 + b1[h];
    float wh2 = d2 + b2[h];
    t1[h][r] = f2bf(wh1);
    Wh2f[(size_t)grow * H + h] = wh2;

    float v1 = wh1 * a1[h];
    float v2 = wh2 * a2[h];
#pragma unroll
    for (int m = 16; m >= 1; m >>= 1) { v1 += __shfl_xor(v1, m); v2 += __shfl_xor(v2, m); }
    if (h == 0) { s1[grow] = v1; s2[grow] = v2; }
    __syncthreads();

    if (tid < 32) {
        *(short8*)(WhT1 + (size_t)tid * N_NODES + row0) = *(const short8*)&t1[tid][0];
    }
}

// ---------------------------------------------------------------------------
// K1b: M[0]=max(s1), M[1]=max(s2), M[2]=min(s2)
// ---------------------------------------------------------------------------
__global__ __launch_bounds__(256) void k1b_max(
    const float* __restrict__ s1, const float* __restrict__ s2, float* __restrict__ M)
{
    int tid = threadIdx.x;
    float m1 = -1e30f, m2 = -1e30f, n2 = 1e30f;
    for (int i = tid; i < N_NODES; i += 256) {
        m1 = fmaxf(m1, s1[i]);
        float v = s2[i];
        m2 = fmaxf(m2, v);
        n2 = fminf(n2, v);
    }
#pragma unroll
    for (int m = 32; m >= 1; m >>= 1) {
        m1 = fmaxf(m1, __shfl_xor(m1, m));
        m2 = fmaxf(m2, __shfl_xor(m2, m));
        n2 = fminf(n2, __shfl_xor(n2, m));
    }
    __shared__ float red[12];
    if ((tid & 63) == 0) {
        int w = tid >> 6;
        red[w * 3] = m1; red[w * 3 + 1] = m2; red[w * 3 + 2] = n2;
    }
    __syncthreads();
    if (tid == 0) {
        float a = red[0], b = red[1], c = red[2];
        for (int w = 1; w < 4; ++w) {
            a = fmaxf(a, red[w * 3]);
            b = fmaxf(b, red[w * 3 + 1]);
            c = fminf(c, red[w * 3 + 2]);
        }
        M[0] = a; M[1] = b; M[2] = c;
    }
}

// ---------------------------------------------------------------------------
// P2zero: zero the bucket accumulator Sc (66 x KB floats)
// ---------------------------------------------------------------------------
__global__ __launch_bounds__(256) void p2zero(float* __restrict__ Sc)
{
    int idx = blockIdx.x * 256 + threadIdx.x;   // 528*256 = 135168 float4 = 540672 f
    ((float4*)Sc)[idx] = make_float4(0.f, 0.f, 0.f, 0.f);
}

// ---------------------------------------------------------------------------
// P2a: bucket-accumulate path 2. Per j: E=exp(s2-M1), F=exp(0.2(s2-M1)),
// b = floor((s2-lo)*invw). Sc[h][b] += E*Wh; Sc[32+h][b] += F*Wh;
// Sc[64][b] += E; Sc[65][b] += F.   grid 1024 x 256 (8 j x 32 h)
// ---------------------------------------------------------------------------
__global__ __launch_bounds__(256) void p2a_bucket(
    const float* __restrict__ s2, const float* __restrict__ Wh2f,
    const float* __restrict__ M, float* __restrict__ Sc)
{
    int tid = threadIdx.x;
    int j = blockIdx.x * 8 + (tid >> 5);
    int h = tid & 31;
    float M1 = M[1], lo = M[2];
    float invw = (float)KB / fmaxf(M1 - lo, 1e-9f);
    float sv = s2[j];
    int b = (int)((sv - lo) * invw);
    b = min(max(b, 0), KB - 1);
    float E = __expf(sv - M1);
    float F = __expf(0.2f * (sv - M1));
    float wh = Wh2f[(size_t)j * H + h];
    atomicAdd(&Sc[(size_t)h * KB + b], E * wh);
    atomicAdd(&Sc[(size_t)(32 + h) * KB + b], F * wh);
    if (h == 0) {
        atomicAdd(&Sc[(size_t)64 * KB + b], E);
        atomicAdd(&Sc[(size_t)65 * KB + b], F);
    }
}

// ---------------------------------------------------------------------------
// P2b1: per-channel per-chunk suffix-inclusive scan (in place).
// grid (66, 8) x 256; chunk = 1024 buckets; writes chunk totals.
// ---------------------------------------------------------------------------
__global__ __launch_bounds__(256) void p2b1_scan(
    float* __restrict__ Sc, float* __restrict__ totals)
{
    int ch = blockIdx.x, chunk = blockIdx.y;
    float* base = Sc + (size_t)ch * KB + chunk * 1024;
    int tid = threadIdx.x;
    int k0 = tid * 4;                 // k = reversed order index
    float x0 = base[1023 - k0];
    float x1 = base[1022 - k0];
    float x2 = base[1021 - k0];
    float x3 = base[1020 - k0];
    float p1 = x0 + x1, p2 = p1 + x2, p3 = p2 + x3;
    float inc = p3;
    int lane = tid & 63;
#pragma unroll
    for (int d = 1; d < 64; d <<= 1) {
        float y = __shfl_up(inc, d);
        if (lane >= d) inc += y;
    }
    __shared__ float wt[4];
    if (lane == 63) wt[tid >> 6] = inc;
    __syncthreads();
    int wv = tid >> 6;
    float woff = 0.f;
    if (wv > 0) woff += wt[0];
    if (wv > 1) woff += wt[1];
    if (wv > 2) woff += wt[2];
    float offv = woff + (inc - p3);   // exclusive over all prior threads
    base[1023 - k0] = x0 + offv;
    base[1022 - k0] = p1 + offv;
    base[1021 - k0] = p2 + offv;
    base[1020 - k0] = p3 + offv;
    if (tid == 255) totals[ch * 8 + chunk] = p3 + offv;
}

// ---------------------------------------------------------------------------
// P2b2: off[ch][c] = sum of totals of chunks AFTER c (suffix-exclusive).
// ---------------------------------------------------------------------------
__global__ __launch_bounds__(128) void p2b2_off(
    const float* __restrict__ totals, float* __restrict__ off)
{
    int tid = threadIdx.x;
    if (tid < NCH) {
        float run = 0.f;
        for (int c = 7; c >= 0; --c) {
            off[tid * 8 + c] = run;
            run += totals[tid * 8 + c];
        }
    }
}

// ---------------------------------------------------------------------------
// K2: path-1 MFMA attention (adjacency-masked). Two-regime select, no exp
// per element. Block: 64 rows x 2048 j (jb 0..3), 512 thr = 8 waves.
// ---------------------------------------------------------------------------
__global__ __launch_bounds__(512) void k2_attn1(
    const float* __restrict__ s1g, const unsigned short* __restrict__ WhT1,
    const int* __restrict__ adj, const float* __restrict__ M,
    float* __restrict__ part1)
{
    __shared__ unsigned short w1[64 * 128];   // 16 KB, XOR-swizzled
    __shared__ unsigned short t1[32 * 128];   // 8 KB, XOR-swizzled
    __shared__ float srow[64], g1r[64], g2r[64];

    int tid = threadIdx.x;
    int row0 = blockIdx.x * 64;
    int jb = blockIdx.y;
    int jstart = jb * 2048;
    float M0 = M[0];

    if (tid < 64) {
        float sv = s1g[row0 + tid];
        srow[tid] = sv;
        float u = sv + M0;
        g1r[tid] = u >= 0.f ? 1.f : __expf(0.8f * u);
        g2r[tid] = u >= 0.f ? __expf(-0.8f * u) : 1.f;
    }
    __syncthreads();

    int wave = tid >> 6;
    int lane = tid & 63;
    int rg = wave >> 1;
    int hg = wave & 1;
    int grp = lane >> 4;

    int arow = rg * 16 + (lane & 15);
    int aswz = (arow & 7) << 4;
    int a_base = arow * 256;
    int brow = hg * 16 + (lane & 15);
    int bswz = (brow & 7) << 4;
    int b_base = brow * 256;

    int sh = tid >> 4, sc = tid & 15;
    int s_byte = (sh * 256 + sc * 16) ^ ((sh & 7) << 4);
    const unsigned short* src1 = WhT1 + (size_t)sh * N_NODES + sc * 8;

    int tcol = (tid & 31) * 4;
    int trh = tid >> 5;                // 0..15
    const int* adjb = adj + (size_t)row0 * N_NODES + tcol;

    f32x4 acc1 = {0.f, 0.f, 0.f, 0.f};
    float l0 = 0.f, l1 = 0.f, l2 = 0.f, l3 = 0.f;

    int4 cA, cB, cC, cD, nA, nB, nC, nD;
    cA = *(const int4*)(adjb + (size_t)(0 * 16 + trh) * N_NODES + jstart);
    cB = *(const int4*)(adjb + (size_t)(1 * 16 + trh) * N_NODES + jstart);
    cC = *(const int4*)(adjb + (size_t)(2 * 16 + trh) * N_NODES + jstart);
    cD = *(const int4*)(adjb + (size_t)(3 * 16 + trh) * N_NODES + jstart);

    for (int jt = 0; jt < 16; ++jt) {
        int j0 = jstart + jt * 128;

        if (jt < 15) {
            int jn = j0 + 128;
            nA = *(const int4*)(adjb + (size_t)(0 * 16 + trh) * N_NODES + jn);
            nB = *(const int4*)(adjb + (size_t)(1 * 16 + trh) * N_NODES + jn);
            nC = *(const int4*)(adjb + (size_t)(2 * 16 + trh) * N_NODES + jn);
            nD = *(const int4*)(adjb + (size_t)(3 * 16 + trh) * N_NODES + jn);
        }

        short8 wv1 = *(const short8*)(src1 + j0);
        *(short8*)((char*)t1 + s_byte) = wv1;

        float4 sj = *(const float4*)(s1g + j0 + tcol);
        float4 e4, f4;
        e4.x = __expf(sj.x - M0); e4.y = __expf(sj.y - M0);
        e4.z = __expf(sj.z - M0); e4.w = __expf(sj.w - M0);
        f4.x = __expf(0.2f * (sj.x - M0)); f4.y = __expf(0.2f * (sj.y - M0));
        f4.z = __expf(0.2f * (sj.z - M0)); f4.w = __expf(0.2f * (sj.w - M0));

#define W_GEN(KK, AV, LL)                                                       \
        {                                                                       \
            int r = KK * 16 + trh;                                              \
            float sr = srow[r], g1v = g1r[r], g2v = g2r[r];                     \
            float4 w;                                                           \
            bool px = sr + sj.x >= 0.f, py = sr + sj.y >= 0.f;                  \
            bool pz = sr + sj.z >= 0.f, pw = sr + sj.w >= 0.f;                  \
            w.x = (px ? g1v : g2v) * (px ? e4.x : f4.x);                        \
            w.y = (py ? g1v : g2v) * (py ? e4.y : f4.y);                        \
            w.z = (pz ? g1v : g2v) * (pz ? e4.z : f4.z);                        \
            w.w = (pw ? g1v : g2v) * (pw ? e4.w : f4.w);                        \
            if (AV.x == 0) w.x = 0.f;                                           \
            if (AV.y == 0) w.y = 0.f;                                           \
            if (AV.z == 0) w.z = 0.f;                                           \
            if (AV.w == 0) w.w = 0.f;                                           \
            LL += (w.x + w.y) + (w.z + w.w);                                    \
            int byte = (r * 256 + tcol * 2) ^ ((r & 7) << 4);                   \
            u16x4 p;                                                            \
            p.x = f2bf(w.x); p.y = f2bf(w.y); p.z = f2bf(w.z); p.w = f2bf(w.w); \
            *(u16x4*)((char*)w1 + byte) = p;                                    \
        }

        W_GEN(0, cA, l0)
        W_GEN(1, cB, l1)
        W_GEN(2, cC, l2)
        W_GEN(3, cD, l3)
#undef W_GEN
        __syncthreads();

#pragma unroll
        for (int ks = 0; ks < 4; ++ks) {
            short8 a = *(const short8*)((const char*)w1 + ((a_base + ks * 64 + grp * 16) ^ aswz));
            short8 b = *(const short8*)((const char*)t1 + ((b_base + ks * 64 + grp * 16) ^ bswz));
            acc1 = __builtin_amdgcn_mfma_f32_16x16x32_bf16(a, b, acc1, 0, 0, 0);
        }
        __syncthreads();

        cA = nA; cB = nB; cC = nC; cD = nD;
    }

#pragma unroll
    for (int reg = 0; reg < 4; ++reg) {
        int grow = row0 + rg * 16 + grp * 4 + reg;
        part1[((size_t)jb * N_NODES + grow) * 33 + hg * 16 + (lane & 15)] = acc1[reg];
    }

#define DEN(KK, DD)                                                             \
    {                                                                           \
        float d = DD;                                                           \
        d += __shfl_xor(d, 1);                                                  \
        d += __shfl_xor(d, 2);                                                  \
        d += __shfl_xor(d, 4);                                                  \
        d += __shfl_xor(d, 8);                                                  \
        d += __shfl_xor(d, 16);                                                 \
        if ((tid & 31) == 0) {                                                  \
            int r = KK * 16 + trh;                                              \
            part1[((size_t)jb * N_NODES + row0 + r) * 33 + 32] = d;             \
        }                                                                       \
    }
    DEN(0, l0)
    DEN(1, l1)
    DEN(2, l2)
    DEN(3, l3)
#undef DEN
}

// ---------------------------------------------------------------------------
// K2b3: path1 z from part1; path2 z from bucket scans; then semantic score
// partials. grid 1024 x 256 (8 rows x 32 h).
// ---------------------------------------------------------------------------
__global__ __launch_bounds__(256) void k2b3(
    const float* __restrict__ part1,
    const float* __restrict__ Sc, const float* __restrict__ off,
    const float* __restrict__ s2g, const float* __restrict__ M,
    const float* __restrict__ Wsw, const float* __restrict__ Wsb,
    const float* __restrict__ bsem, const float* __restrict__ q,
    float* __restrict__ z1, float* __restrict__ z2, float* __restrict__ partial)
{
    __shared__ float zl1[256], zl2[256];
    __shared__ float rowsum[8];
    int tid = threadIdx.x;
    int row0 = blockIdx.x * 8;
    int r = tid >> 5, h = tid & 31;
    int row = row0 + r;

    // ---- path 1 ----
    float n1 = 0.f, d1 = 0.f;
#pragma unroll
    for (int jb = 0; jb < 4; ++jb) {
        size_t base = ((size_t)jb * N_NODES + row) * 33;
        n1 += part1[base + h]; d1 += part1[base + 32];
    }
    float z1v = sigmoidf_(d1 > 0.f ? n1 / d1 : 0.f);

    // ---- path 2 via suffix scans ----
    float M1 = M[1], lo = M[2];
    float invw = (float)KB / fmaxf(M1 - lo, 1e-9f);
    float sv = s2g[row];
    float t = -sv;
    int bt = (int)roundf((t - lo) * invw);
    bt = min(max(bt, 0), KB);
    float u = sv + M1;
    float g1 = u >= 0.f ? 1.f : __expf(0.8f * u);
    float g2 = u >= 0.f ? __expf(-0.8f * u) : 1.f;

#define GATHER(CH, B) ((B) >= KB ? 0.f : Sc[(size_t)(CH) * KB + (B)] + off[(CH) * 8 + ((B) >> 10)])
    float SufE  = GATHER(h, bt);
    float SufF  = GATHER(32 + h, bt);
    float TotF  = GATHER(32 + h, 0);
    float SufEs = GATHER(64, bt);
    float SufFs = GATHER(65, bt);
    float TotFs = GATHER(65, 0);
#undef GATHER
    float num2 = g1 * SufE + g2 * (TotF - SufF);
    float den2 = g1 * SufEs + g2 * (TotFs - SufFs);
    float z2v = sigmoidf_(num2 / fmaxf(den2, 1e-30f));

    size_t gi = (size_t)row * H + h;
    z1[gi] = z1v;
    z2[gi] = z2v;
    zl1[tid] = z1v;
    zl2[tid] = z2v;
    __syncthreads();

    // ---- semantic score partials ----
    const float* wr = Wsw + h * H;
    for (int p = 0; p < 2; ++p) {
        const float* zl = p ? zl2 : zl1;
        float d = 0.f;
        const float* zr = zl + r * H;
#pragma unroll
        for (int k = 0; k < H; ++k) d += zr[k] * wr[k];
        float val = tanh_fast(d + Wsb[h] + bsem[h]) * q[h];
#pragma unroll
        for (int m = 16; m >= 1; m >>= 1) val += __shfl_xor(val, m);
        if (h == 0) rowsum[r] = val;
        __syncthreads();
        if (tid == 0) {
            float s = 0.f;
#pragma unroll
            for (int i = 0; i < 8; ++i) s += rowsum[i];
            partial[p * 1024 + blockIdx.x] = s;
        }
        __syncthreads();
    }
}

// ---------------------------------------------------------------------------
// K3b: sum partials -> beta (softmax over 2)
// ---------------------------------------------------------------------------
__global__ __launch_bounds__(256) void k3b_beta(
    const float* __restrict__ partial, float* __restrict__ beta)
{
    int tid = threadIdx.x;
    float s1 = 0.f, s2 = 0.f;
    for (int i = tid; i < 1024; i += 256) { s1 += partial[i]; s2 += partial[1024 + i]; }
#pragma unroll
    for (int m = 32; m >= 1; m >>= 1) { s1 += __shfl_xor(s1, m); s2 += __shfl_xor(s2, m); }
    __shared__ float red[8];
    if ((tid & 63) == 0) { red[(tid >> 6) * 2] = s1; red[(tid >> 6) * 2 + 1] = s2; }
    __syncthreads();
    if (tid == 0) {
        float a = red[0] + red[2] + red[4] + red[6];
        float b = red[1] + red[3] + red[5] + red[7];
        a /= (float)N_NODES;
        b /= (float)N_NODES;
        float mx = fmaxf(a, b);
        float e1 = __expf(a - mx), e2 = __expf(b - mx);
        float inv = 1.f / (e1 + e2);
        beta[0] = e1 * inv;
        beta[1] = e2 * inv;
    }
}

// ---------------------------------------------------------------------------
// K4: z_final = b0*z1 + b1*z2 ; logits = z_final @ cls_w^T + cls_b
// ---------------------------------------------------------------------------
__global__ __launch_bounds__(256) void k4_final(
    const float* __restrict__ z1, const float* __restrict__ z2,
    const float* __restrict__ beta,
    const float* __restrict__ clsw, const float* __restrict__ clsb,
    float* __restrict__ out)
{
    int tid = threadIdx.x;
    int row0 = blockIdx.x * 8;
    int r = tid >> 5, h = tid & 31;
    int grow = row0 + r;
    size_t gi = (size_t)grow * H + h;
    float b0 = beta[0], b1 = beta[1];
    float zf = b0 * z1[gi] + b1 * z2[gi];
    out[gi] = zf;
    float p0 = zf * clsw[h];
    float p1 = zf * clsw[H + h];
#pragma unroll
    for (int m = 16; m >= 1; m >>= 1) { p0 += __shfl_xor(p0, m); p1 += __shfl_xor(p1, m); }
    if (h == 0) {
        out[(size_t)N_NODES * H + (size_t)grow * 2]     = p0 + clsb[0];
        out[(size_t)N_NODES * H + (size_t)grow * 2 + 1] = p1 + clsb[1];
    }
}

extern "C" void kernel_launch(void* const* d_in, const int* in_sizes, int n_in,
                              void* d_out, int out_size, void* d_ws, size_t ws_size,
                              hipStream_t stream)
{
    const float* x    = (const float*)d_in[0];
    const float* W1   = (const float*)d_in[1];
    const float* b1   = (const float*)d_in[2];
    const float* a1   = (const float*)d_in[3];
    const float* W2   = (const float*)d_in[4];
    const float* b2   = (const float*)d_in[5];
    const float* a2   = (const float*)d_in[6];
    const float* q    = (const float*)d_in[7];
    const float* Wsw  = (const float*)d_in[8];
    const float* Wsb  = (const float*)d_in[9];
    const float* bsem = (const float*)d_in[10];
    const float* clsw = (const float*)d_in[11];
    const float* clsb = (const float*)d_in[12];
    const int*   adj  = (const int*)d_in[13];
    // d_in[14] = mg_adj : unused

    // Workspace layout in FLOAT units.
    float* ws = (float*)d_ws;
    unsigned short* WhT1 = (unsigned short*)ws;        // floats [0, 131072)  (bf16 H x N)
    float* Wh2f   = ws + 131072;                       // 262144 (f32 N x H)
    float* s1     = ws + 393216;                       // 8192
    float* s2     = s1 + N_NODES;                      // 8192
    float* M      = s2 + N_NODES;                      // 8 (3 used)
    float* beta   = M + 8;                             // 8 (2 used)
    float* partial= beta + 8;                          // 2048
    float* z1     = partial + 2048;                    // 262144
    float* z2     = z1 + N_NODES * H;                  // 262144
    float* part1  = z2 + N_NODES * H;                  // 4*8192*33 = 1081344
    float* Sc     = part1 + 4 * N_NODES * 33;          // 66*8192 = 540672
    float* totals = Sc + (size_t)NCH * KB;             // 528
    float* offb   = totals + NCH * 8;                  // 528
    // total ~= 10.2 MB

    float* out = (float*)d_out;

    hipLaunchKernelGGL(k1_wh_s, dim3(1024), dim3(256), 0, stream,
                       x, W1, b1, a1, W2, b2, a2, WhT1, Wh2f, s1, s2);
    hipLaunchKernelGGL(k1b_max, dim3(1), dim3(256), 0, stream, s1, s2, M);

    // path-2 bucket pipeline
    hipLaunchKernelGGL(p2zero, dim3(528), dim3(256), 0, stream, Sc);
    hipLaunchKernelGGL(p2a_bucket, dim3(1024), dim3(256), 0, stream, s2, Wh2f, M, Sc);
    hipLaunchKernelGGL(p2b1_scan, dim3(NCH, 8), dim3(256), 0, stream, Sc, totals);
    hipLaunchKernelGGL(p2b2_off, dim3(1), dim3(128), 0, stream, totals, offb);

    // path-1 MFMA attention
    hipLaunchKernelGGL(k2_attn1, dim3(128, 4), dim3(512), 0, stream,
                       s1, WhT1, adj, M, part1);

    hipLaunchKernelGGL(k2b3, dim3(1024), dim3(256), 0, stream,
                       part1, Sc, offb, s2, M, Wsw, Wsb, bsem, q, z1, z2, partial);

    hipLaunchKernelGGL(k3b_beta, dim3(1), dim3(256), 0, stream, partial, beta);
    hipLaunchKernelGGL(k4_final, dim3(1024), dim3(256), 0, stream,
                       z1, z2, beta, clsw, clsb, out);
}

// Round 6
// 149.028 us; speedup vs baseline: 3.1466x; 1.0160x over previous
//
#include <hip/hip_runtime.h>
#include <cstdint>
#include <cstddef>

#define N_NODES 8192
#define IN_DIM 128
#define H 32
#define KB 8192          // path-2 buckets
#define NCH 66           // 32 E*Wh + 32 F*Wh + E + F channels

typedef __attribute__((ext_vector_type(8))) short short8;
typedef __attribute__((ext_vector_type(4))) float f32x4;

__device__ __forceinline__ float lrelu(float x) { return x >= 0.0f ? x : 0.2f * x; }
__device__ __forceinline__ float sigmoidf_(float x) { return 1.0f / (1.0f + __expf(-x)); }
__device__ __forceinline__ float tanh_fast(float x) { return 1.0f - 2.0f / (1.0f + __expf(2.0f * x)); }
__device__ __forceinline__ unsigned short f2bf(float f) {
    unsigned u = __float_as_uint(f);
    unsigned r = (u + 0x7fffu + ((u >> 16) & 1u)) >> 16;
    return (unsigned short)r;
}
// pack two f32 -> one u32 of 2 bf16 (lo|hi<<16), round-to-nearest (ties down).
// v_perm_b32: sel idx 0-3 from S1, 4-7 from S0. D.b0=a.b2 D.b1=a.b3 D.b2=b.b2 D.b3=b.b3
__device__ __forceinline__ unsigned pack_bf_pair(float lo, float hi) {
    unsigned a = __float_as_uint(lo) + 0x7FFFu;
    unsigned b = __float_as_uint(hi) + 0x7FFFu;
    return __builtin_amdgcn_perm(b, a, 0x07060302u);
}

// ---------------------------------------------------------------------------
// K1: Wh = x@W^T + b for both paths. Path1 -> WhT1 bf16 (H x N) for MFMA.
// Path2 -> Wh2f f32 (N x H). s = Wh@a. Also zeroes Sc (bucket accumulator).
// ---------------------------------------------------------------------------
__global__ __launch_bounds__(256) void k1_wh_s(
    const float* __restrict__ x,
    const float* __restrict__ W1, const float* __restrict__ b1, const float* __restrict__ a1,
    const float* __restrict__ W2, const float* __restrict__ b2, const float* __restrict__ a2,
    unsigned short* __restrict__ WhT1, float* __restrict__ Wh2f,
    float* __restrict__ s1, float* __restrict__ s2, float* __restrict__ Sc)
{
    __shared__ float xl[8 * IN_DIM];
    __shared__ __align__(16) unsigned short t1[32][8];
    int tid = threadIdx.x;
    int row0 = blockIdx.x * 8;

    // zero Sc: 66*8192 floats = 135168 float4 over 262144 threads
    {
        int idx = blockIdx.x * 256 + tid;
        if (idx < (NCH * KB) / 4)
            ((float4*)Sc)[idx] = make_float4(0.f, 0.f, 0.f, 0.f);
    }

    ((float4*)xl)[tid] = ((const float4*)(x + (size_t)row0 * IN_DIM))[tid];
    __syncthreads();

    int r = tid >> 5, h = tid & 31;
    const float* xr = xl + r * IN_DIM;
    const float* w1r = W1 + h * IN_DIM;
    const float* w2r = W2 + h * IN_DIM;
    float d1 = 0.f, d2 = 0.f;
#pragma unroll 8
    for (int k = 0; k < IN_DIM; k += 4) {
        float4 xv = *(const float4*)(xr + k);
        float4 wa = *(const float4*)(w1r + k);
        float4 wb = *(const float4*)(w2r + k);
        d1 += xv.x * wa.x + xv.y * wa.y + xv.z * wa.z + xv.w * wa.w;
        d2 += xv.x * wb.x + xv.y * wb.y + xv.z * wb.z + xv.w * wb.w;
    }
    int grow = row0 + r;
    float wh1 = d1 + b1[h];
    float wh2 = d2 + b2[h];
    t1[h][r] = f2bf(wh1);
    Wh2f[(size_t)grow * H + h] = wh2;

    float v1 = wh1 * a1[h];
    float v2 = wh2 * a2[h];
#pragma unroll
    for (int m = 16; m >= 1; m >>= 1) { v1 += __shfl_xor(v1, m); v2 += __shfl_xor(v2, m); }
    if (h == 0) { s1[grow] = v1; s2[grow] = v2; }
    __syncthreads();

    if (tid < 32) {
        *(short8*)(WhT1 + (size_t)tid * N_NODES + row0) = *(const short8*)&t1[tid][0];
    }
}

// ---------------------------------------------------------------------------
// K1b: M[0]=max(s1), M[1]=max(s2), M[2]=min(s2)
// ---------------------------------------------------------------------------
__global__ __launch_bounds__(256) void k1b_max(
    const float* __restrict__ s1, const float* __restrict__ s2, float* __restrict__ M)
{
    int tid = threadIdx.x;
    float m1 = -1e30f, m2 = -1e30f, n2 = 1e30f;
    for (int i = tid; i < N_NODES; i += 256) {
        m1 = fmaxf(m1, s1[i]);
        float v = s2[i];
        m2 = fmaxf(m2, v);
        n2 = fminf(n2, v);
    }
#pragma unroll
    for (int m = 32; m >= 1; m >>= 1) {
        m1 = fmaxf(m1, __shfl_xor(m1, m));
        m2 = fmaxf(m2, __shfl_xor(m2, m));
        n2 = fminf(n2, __shfl_xor(n2, m));
    }
    __shared__ float red[12];
    if ((tid & 63) == 0) {
        int w = tid >> 6;
        red[w * 3] = m1; red[w * 3 + 1] = m2; red[w * 3 + 2] = n2;
    }
    __syncthreads();
    if (tid == 0) {
        float a = red[0], b = red[1], c = red[2];
        for (int w = 1; w < 4; ++w) {
            a = fmaxf(a, red[w * 3]);
            b = fmaxf(b, red[w * 3 + 1]);
            c = fminf(c, red[w * 3 + 2]);
        }
        M[0] = a; M[1] = b; M[2] = c;
    }
}

// ---------------------------------------------------------------------------
// P2a: bucket-accumulate path 2. grid 1024 x 256 (8 j x 32 h)
// ---------------------------------------------------------------------------
__global__ __launch_bounds__(256) void p2a_bucket(
    const float* __restrict__ s2, const float* __restrict__ Wh2f,
    const float* __restrict__ M, float* __restrict__ Sc)
{
    int tid = threadIdx.x;
    int j = blockIdx.x * 8 + (tid >> 5);
    int h = tid & 31;
    float M1 = M[1], lo = M[2];
    float invw = (float)KB / fmaxf(M1 - lo, 1e-9f);
    float sv = s2[j];
    int b = (int)((sv - lo) * invw);
    b = min(max(b, 0), KB - 1);
    float E = __expf(sv - M1);
    float F = __expf(0.2f * (sv - M1));
    float wh = Wh2f[(size_t)j * H + h];
    atomicAdd(&Sc[(size_t)h * KB + b], E * wh);
    atomicAdd(&Sc[(size_t)(32 + h) * KB + b], F * wh);
    if (h == 0) {
        atomicAdd(&Sc[(size_t)64 * KB + b], E);
        atomicAdd(&Sc[(size_t)65 * KB + b], F);
    }
}

// ---------------------------------------------------------------------------
// P2b: full-channel suffix-inclusive scan in place (carried across 8 chunks).
// grid 66 x 256.
// ---------------------------------------------------------------------------
__global__ __launch_bounds__(256) void p2b_scan(float* __restrict__ Sc)
{
    int ch = blockIdx.x;
    float* chb = Sc + (size_t)ch * KB;
    int tid = threadIdx.x;
    int lane = tid & 63;
    __shared__ float wt[4];
    __shared__ float sCarry;
    float carry = 0.f;

    for (int chunk = 7; chunk >= 0; --chunk) {
        float* base = chb + chunk * 1024;
        int k0 = tid * 4;
        float x0 = base[1023 - k0];
        float x1 = base[1022 - k0];
        float x2 = base[1021 - k0];
        float x3 = base[1020 - k0];
        float p1 = x0 + x1, p2 = p1 + x2, p3 = p2 + x3;
        float inc = p3;
#pragma unroll
        for (int d = 1; d < 64; d <<= 1) {
            float y = __shfl_up(inc, d);
            if (lane >= d) inc += y;
        }
        if (lane == 63) wt[tid >> 6] = inc;
        __syncthreads();
        int wv = tid >> 6;
        float woff = carry;
        if (wv > 0) woff += wt[0];
        if (wv > 1) woff += wt[1];
        if (wv > 2) woff += wt[2];
        float offv = woff + (inc - p3);
        base[1023 - k0] = x0 + offv;
        base[1022 - k0] = p1 + offv;
        base[1021 - k0] = p2 + offv;
        base[1020 - k0] = p3 + offv;
        if (tid == 255) sCarry = p3 + offv;
        __syncthreads();
        carry = sCarry;
    }
}

// ---------------------------------------------------------------------------
// K2: path-1 MFMA attention, double-buffered LDS, ONE barrier per j-tile.
// Block: 64 rows x 2048 j (jb 0..3), 512 thr = 8 waves.
// Pipeline at iter jt: barrier; [loads for jt+1/jt+2]; MFMA buf[cur];
// W_GEN(jt+1)->buf[cur^1]. Adjacency regs are 2-deep (c = tile jt+1).
// ---------------------------------------------------------------------------
__global__ __launch_bounds__(512) void k2_attn1(
    const float* __restrict__ s1g, const unsigned short* __restrict__ WhT1,
    const int* __restrict__ adj, const float* __restrict__ M,
    float* __restrict__ num1, float* __restrict__ den1)
{
    __shared__ unsigned short w_lds[2][64 * 128];   // 2 x 16 KB, XOR-swizzled
    __shared__ unsigned short t_lds[2][32 * 128];   // 2 x 8 KB, XOR-swizzled
    __shared__ float srow[64], g1r[64], g2r[64];

    int tid = threadIdx.x;
    int row0 = blockIdx.x * 64;
    int jb = blockIdx.y;
    int jstart = jb * 2048;
    float M0 = M[0];

    if (tid < 64) {
        float sv = s1g[row0 + tid];
        srow[tid] = sv;
        float u = sv + M0;
        g1r[tid] = u >= 0.f ? 1.f : __expf(0.8f * u);
        g2r[tid] = u >= 0.f ? __expf(-0.8f * u) : 1.f;
    }
    __syncthreads();

    int wave = tid >> 6;
    int lane = tid & 63;
    int rg = wave >> 1;
    int hg = wave & 1;
    int grp = lane >> 4;

    int arow = rg * 16 + (lane & 15);
    int aswz = (arow & 7) << 4;
    int a_base = arow * 256;
    int brow = hg * 16 + (lane & 15);
    int bswz = (brow & 7) << 4;
    int b_base = brow * 256;

    int sh = tid >> 4, sc = tid & 15;
    int s_byte = (sh * 256 + sc * 16) ^ ((sh & 7) << 4);
    const unsigned short* src1 = WhT1 + (size_t)sh * N_NODES + sc * 8;

    int tcol = (tid & 31) * 4;
    int trh = tid >> 5;                // 0..15
    const int* adjb = adj + (size_t)row0 * N_NODES + tcol;

    f32x4 acc1 = {0.f, 0.f, 0.f, 0.f};
    float l0 = 0.f, l1 = 0.f, l2 = 0.f, l3 = 0.f;

    int4 cA, cB, cC, cD, nA, nB, nC, nD;
    float4 sj, e4, f4;

#define W_GEN(KK, AV, LL, WB)                                                   \
        {                                                                       \
            int r = KK * 16 + trh;                                              \
            float sr = srow[r], g1v = g1r[r], g2v = g2r[r];                     \
            bool px = sr + sj.x >= 0.f, py = sr + sj.y >= 0.f;                  \
            bool pz = sr + sj.z >= 0.f, pw = sr + sj.w >= 0.f;                  \
            float wx = (px ? g1v : g2v) * (px ? e4.x : f4.x);                   \
            float wy = (py ? g1v : g2v) * (py ? e4.y : f4.y);                   \
            float wz = (pz ? g1v : g2v) * (pz ? e4.z : f4.z);                   \
            float ww = (pw ? g1v : g2v) * (pw ? e4.w : f4.w);                   \
            if (AV.x == 0) wx = 0.f;                                            \
            if (AV.y == 0) wy = 0.f;                                            \
            if (AV.z == 0) wz = 0.f;                                            \
            if (AV.w == 0) ww = 0.f;                                            \
            LL += (wx + wy) + (wz + ww);                                        \
            uint2 pk;                                                           \
            pk.x = pack_bf_pair(wx, wy);                                        \
            pk.y = pack_bf_pair(wz, ww);                                        \
            int byte = (r * 256 + tcol * 2) ^ ((r & 7) << 4);                   \
            *(uint2*)((char*)(WB) + byte) = pk;                                 \
        }

#define EF_GEN(J0)                                                              \
        {                                                                       \
            sj = *(const float4*)(s1g + (J0) + tcol);                           \
            e4.x = __expf(sj.x - M0); e4.y = __expf(sj.y - M0);                 \
            e4.z = __expf(sj.z - M0); e4.w = __expf(sj.w - M0);                 \
            f4.x = __expf(0.2f * (sj.x - M0)); f4.y = __expf(0.2f * (sj.y - M0)); \
            f4.z = __expf(0.2f * (sj.z - M0)); f4.w = __expf(0.2f * (sj.w - M0)); \
        }

#define ADJ_LOAD(DA, DB, DC, DD, J0)                                            \
        {                                                                       \
            DA = *(const int4*)(adjb + (size_t)(0 * 16 + trh) * N_NODES + (J0)); \
            DB = *(const int4*)(adjb + (size_t)(1 * 16 + trh) * N_NODES + (J0)); \
            DC = *(const int4*)(adjb + (size_t)(2 * 16 + trh) * N_NODES + (J0)); \
            DD = *(const int4*)(adjb + (size_t)(3 * 16 + trh) * N_NODES + (J0)); \
        }

    // ---- prologue: tile 0 into buf0; preload adjacency tile 1 ----
    ADJ_LOAD(cA, cB, cC, cD, jstart)
    {
        short8 whv = *(const short8*)(src1 + jstart);
        *(short8*)((char*)t_lds[0] + s_byte) = whv;
    }
    EF_GEN(jstart)
    W_GEN(0, cA, l0, w_lds[0])
    W_GEN(1, cB, l1, w_lds[0])
    W_GEN(2, cC, l2, w_lds[0])
    W_GEN(3, cD, l3, w_lds[0])
    ADJ_LOAD(cA, cB, cC, cD, jstart + 128)

    int cur = 0;
    for (int jt = 0; jt < 16; ++jt) {
        __syncthreads();           // buf[cur] complete for all waves
        int nb = cur ^ 1;
        short8 whv;

        if (jt < 14) {             // adjacency for tile jt+2 (2-deep pipeline)
            ADJ_LOAD(nA, nB, nC, nD, jstart + (jt + 2) * 128)
        }
        if (jt < 15) {
            whv = *(const short8*)(src1 + jstart + (jt + 1) * 128);
            EF_GEN(jstart + (jt + 1) * 128)
        }

        // MFMA on current buffer (independent of the loads above)
        {
            const char* wb = (const char*)w_lds[cur];
            const char* tb = (const char*)t_lds[cur];
#pragma unroll
            for (int ks = 0; ks < 4; ++ks) {
                short8 a = *(const short8*)(wb + ((a_base + ks * 64 + grp * 16) ^ aswz));
                short8 b = *(const short8*)(tb + ((b_base + ks * 64 + grp * 16) ^ bswz));
                acc1 = __builtin_amdgcn_mfma_f32_16x16x32_bf16(a, b, acc1, 0, 0, 0);
            }
        }

        if (jt < 15) {
            *(short8*)((char*)t_lds[nb] + s_byte) = whv;
            W_GEN(0, cA, l0, w_lds[nb])
            W_GEN(1, cB, l1, w_lds[nb])
            W_GEN(2, cC, l2, w_lds[nb])
            W_GEN(3, cD, l3, w_lds[nb])
            if (jt < 14) { cA = nA; cB = nB; cC = nC; cD = nD; }
        }
        cur = nb;
    }
#undef W_GEN
#undef EF_GEN
#undef ADJ_LOAD

    // numerators: C/D layout col=lane&15 (h), row=(lane>>4)*4+reg
#pragma unroll
    for (int reg = 0; reg < 4; ++reg) {
        int grow = row0 + rg * 16 + grp * 4 + reg;
        num1[((size_t)jb * N_NODES + grow) * 32 + hg * 16 + (lane & 15)] = acc1[reg];
    }

#define DEN(KK, DD)                                                             \
    {                                                                           \
        float d = DD;                                                           \
        d += __shfl_xor(d, 1);                                                  \
        d += __shfl_xor(d, 2);                                                  \
        d += __shfl_xor(d, 4);                                                  \
        d += __shfl_xor(d, 8);                                                  \
        d += __shfl_xor(d, 16);                                                 \
        if ((tid & 31) == 0) {                                                  \
            int r = KK * 16 + trh;                                              \
            den1[(size_t)jb * N_NODES + row0 + r] = d;                          \
        }                                                                       \
    }
    DEN(0, l0)
    DEN(1, l1)
    DEN(2, l2)
    DEN(3, l3)
#undef DEN
}

// ---------------------------------------------------------------------------
// K2b3: path1 z from num1/den1; path2 z from bucket suffix scans; then
// semantic score partials. grid 1024 x 256 (8 rows x 32 h).
// ---------------------------------------------------------------------------
__global__ __launch_bounds__(256) void k2b3(
    const float* __restrict__ num1, const float* __restrict__ den1,
    const float* __restrict__ Sc,
    const float* __restrict__ s2g, const float* __restrict__ M,
    const float* __restrict__ Wsw, const float* __restrict__ Wsb,
    const float* __restrict__ bsem, const float* __restrict__ q,
    float* __restrict__ z1, float* __restrict__ z2, float* __restrict__ partial)
{
    __shared__ float zl1[256], zl2[256];
    __shared__ float rowsum[8];
    int tid = threadIdx.x;
    int row0 = blockIdx.x * 8;
    int r = tid >> 5, h = tid & 31;
    int row = row0 + r;

    // ---- path 1 ----
    float n1 = 0.f, d1 = 0.f;
#pragma unroll
    for (int jb = 0; jb < 4; ++jb) {
        n1 += num1[((size_t)jb * N_NODES + row) * 32 + h];
        d1 += den1[(size_t)jb * N_NODES + row];
    }
    float z1v = sigmoidf_(d1 > 0.f ? n1 / d1 : 0.f);

    // ---- path 2 via suffix scans ----
    float M1 = M[1], lo = M[2];
    float invw = (float)KB / fmaxf(M1 - lo, 1e-9f);
    float sv = s2g[row];
    float t = -sv;
    int bt = (int)roundf((t - lo) * invw);
    bt = min(max(bt, 0), KB);
    float u = sv + M1;
    float g1 = u >= 0.f ? 1.f : __expf(0.8f * u);
    float g2 = u >= 0.f ? __expf(-0.8f * u) : 1.f;

#define GATHER(CH, B) ((B) >= KB ? 0.f : Sc[(size_t)(CH) * KB + (B)])
    float SufE  = GATHER(h, bt);
    float SufF  = GATHER(32 + h, bt);
    float TotF  = GATHER(32 + h, 0);
    float SufEs = GATHER(64, bt);
    float SufFs = GATHER(65, bt);
    float TotFs = GATHER(65, 0);
#undef GATHER
    float num2 = g1 * SufE + g2 * (TotF - SufF);
    float den2 = g1 * SufEs + g2 * (TotFs - SufFs);
    float z2v = sigmoidf_(num2 / fmaxf(den2, 1e-30f));

    size_t gi = (size_t)row * H + h;
    z1[gi] = z1v;
    z2[gi] = z2v;
    zl1[tid] = z1v;
    zl2[tid] = z2v;
    __syncthreads();

    // ---- semantic score partials ----
    const float* wr = Wsw + h * H;
    for (int p = 0; p < 2; ++p) {
        const float* zl = p ? zl2 : zl1;
        float d = 0.f;
        const float* zr = zl + r * H;
#pragma unroll
        for (int k = 0; k < H; ++k) d += zr[k] * wr[k];
        float val = tanh_fast(d + Wsb[h] + bsem[h]) * q[h];
#pragma unroll
        for (int m = 16; m >= 1; m >>= 1) val += __shfl_xor(val, m);
        if (h == 0) rowsum[r] = val;
        __syncthreads();
        if (tid == 0) {
            float s = 0.f;
#pragma unroll
            for (int i = 0; i < 8; ++i) s += rowsum[i];
            partial[p * 1024 + blockIdx.x] = s;
        }
        __syncthreads();
    }
}

// ---------------------------------------------------------------------------
// K3b: sum partials -> beta (softmax over 2)
// ---------------------------------------------------------------------------
__global__ __launch_bounds__(256) void k3b_beta(
    const float* __restrict__ partial, float* __restrict__ beta)
{
    int tid = threadIdx.x;
    float s1 = 0.f, s2 = 0.f;
    for (int i = tid; i < 1024; i += 256) { s1 += partial[i]; s2 += partial[1024 + i]; }
#pragma unroll
    for (int m = 32; m >= 1; m >>= 1) { s1 += __shfl_xor(s1, m); s2 += __shfl_xor(s2, m); }
    __shared__ float red[8];
    if ((tid & 63) == 0) { red[(tid >> 6) * 2] = s1; red[(tid >> 6) * 2 + 1] = s2; }
    __syncthreads();
    if (tid == 0) {
        float a = red[0] + red[2] + red[4] + red[6];
        float b = red[1] + red[3] + red[5] + red[7];
        a /= (float)N_NODES;
        b /= (float)N_NODES;
        float mx = fmaxf(a, b);
        float e1 = __expf(a - mx), e2 = __expf(b - mx);
        float inv = 1.f / (e1 + e2);
        beta[0] = e1 * inv;
        beta[1] = e2 * inv;
    }
}

// ---------------------------------------------------------------------------
// K4: z_final = b0*z1 + b1*z2 ; logits = z_final @ cls_w^T + cls_b
// ---------------------------------------------------------------------------
__global__ __launch_bounds__(256) void k4_final(
    const float* __restrict__ z1, const float* __restrict__ z2,
    const float* __restrict__ beta,
    const float* __restrict__ clsw, const float* __restrict__ clsb,
    float* __restrict__ out)
{
    int tid = threadIdx.x;
    int row0 = blockIdx.x * 8;
    int r = tid >> 5, h = tid & 31;
    int grow = row0 + r;
    size_t gi = (size_t)grow * H + h;
    float b0 = beta[0], b1 = beta[1];
    float zf = b0 * z1[gi] + b1 * z2[gi];
    out[gi] = zf;
    float p0 = zf * clsw[h];
    float p1 = zf * clsw[H + h];
#pragma unroll
    for (int m = 16; m >= 1; m >>= 1) { p0 += __shfl_xor(p0, m); p1 += __shfl_xor(p1, m); }
    if (h == 0) {
        out[(size_t)N_NODES * H + (size_t)grow * 2]     = p0 + clsb[0];
        out[(size_t)N_NODES * H + (size_t)grow * 2 + 1] = p1 + clsb[1];
    }
}

extern "C" void kernel_launch(void* const* d_in, const int* in_sizes, int n_in,
                              void* d_out, int out_size, void* d_ws, size_t ws_size,
                              hipStream_t stream)
{
    const float* x    = (const float*)d_in[0];
    const float* W1   = (const float*)d_in[1];
    const float* b1   = (const float*)d_in[2];
    const float* a1   = (const float*)d_in[3];
    const float* W2   = (const float*)d_in[4];
    const float* b2   = (const float*)d_in[5];
    const float* a2   = (const float*)d_in[6];
    const float* q    = (const float*)d_in[7];
    const float* Wsw  = (const float*)d_in[8];
    const float* Wsb  = (const float*)d_in[9];
    const float* bsem = (const float*)d_in[10];
    const float* clsw = (const float*)d_in[11];
    const float* clsb = (const float*)d_in[12];
    const int*   adj  = (const int*)d_in[13];
    // d_in[14] = mg_adj : unused

    // Workspace layout in FLOAT units.
    float* ws = (float*)d_ws;
    unsigned short* WhT1 = (unsigned short*)ws;        // floats [0, 131072) (bf16 H x N)
    float* Wh2f   = ws + 131072;                       // 262144 (f32 N x H)
    float* s1     = ws + 393216;                       // 8192
    float* s2     = s1 + N_NODES;                      // 8192
    float* M      = s2 + N_NODES;                      // 8 (3 used)
    float* beta   = M + 8;                             // 8 (2 used)
    float* partial= beta + 8;                          // 2048
    float* z1     = partial + 2048;                    // 262144
    float* z2     = z1 + N_NODES * H;                  // 262144
    float* num1   = z2 + N_NODES * H;                  // 4*8192*32 = 1048576
    float* den1   = num1 + 4 * N_NODES * 32;           // 4*8192 = 32768
    float* Sc     = den1 + 4 * N_NODES;                // 66*8192 = 540672
    // total ~= 2.5M floats ~= 10 MB

    float* out = (float*)d_out;

    hipLaunchKernelGGL(k1_wh_s, dim3(1024), dim3(256), 0, stream,
                       x, W1, b1, a1, W2, b2, a2, WhT1, Wh2f, s1, s2, Sc);
    hipLaunchKernelGGL(k1b_max, dim3(1), dim3(256), 0, stream, s1, s2, M);

    // path-2 bucket pipeline
    hipLaunchKernelGGL(p2a_bucket, dim3(1024), dim3(256), 0, stream, s2, Wh2f, M, Sc);
    hipLaunchKernelGGL(p2b_scan, dim3(NCH), dim3(256), 0, stream, Sc);

    // path-1 MFMA attention
    hipLaunchKernelGGL(k2_attn1, dim3(128, 4), dim3(512), 0, stream,
                       s1, WhT1, adj, M, num1, den1);

    hipLaunchKernelGGL(k2b3, dim3(1024), dim3(256), 0, stream,
                       num1, den1, Sc, s2, M, Wsw, Wsb, bsem, q, z1, z2, partial);

    hipLaunchKernelGGL(k3b_beta, dim3(1), dim3(256), 0, stream, partial, beta);
    hipLaunchKernelGGL(k4_final, dim3(1024), dim3(256), 0, stream,
                       z1, z2, beta, clsw, clsb, out);
}